// Round 1
// baseline (1524.846 us; speedup 1.0000x reference)
//
#include <hip/hip_runtime.h>
#include <math.h>

#define TT 2048   // tokens
#define Dm 1024   // model dim
#define DGc 256   // gate dim
#define Ec 8      // experts
#define Nc 9      // graph nodes
#define Lc 3      // GCN layers
#define Hc 2048   // FFN hidden

__device__ __forceinline__ float silu_f(float x) { return x / (1.f + __expf(-x)); }

// ---- init: loss tail rows (count / lamb / theta) + zero expert counters ----
__global__ void k_init(const float* count, const float* lamb, const float* theta,
                       float* out, int* cnt) {
    int i = threadIdx.x;
    float* loss = out + (size_t)TT * Dm;
    if (i < Ec)            loss[(size_t)TT * Ec + i]            = count[i];
    else if (i < 2 * Ec)   loss[(size_t)(TT + 1) * Ec + (i - Ec)]   = lamb[0];
    else if (i < 3 * Ec)   loss[(size_t)(TT + 2) * Ec + (i - 2*Ec)] = theta[0];
    if (i < Ec) cnt[i] = 0;
}

// ---- expert embeddings: expg = silu(X @ W_struct)  [8,256] ----
__global__ __launch_bounds__(256) void k_expg(const float* X, const float* Wst, float* expg) {
    __shared__ float xs[Ec * Dm];
    int g = threadIdx.x;
    for (int i = 0; i < Ec * Dm / 256; i++) xs[i * 256 + g] = X[i * 256 + g];
    __syncthreads();
    float acc[Ec];
#pragma unroll
    for (int e = 0; e < Ec; e++) acc[e] = 0.f;
    for (int k = 0; k < Dm; k++) {
        float w = Wst[k * DGc + g];
#pragma unroll
        for (int e = 0; e < Ec; e++) acc[e] += xs[e * Dm + k] * w;
    }
#pragma unroll
    for (int e = 0; e < Ec; e++) expg[e * DGc + g] = silu_f(acc[e]);
}

// ---- per-token: xg, 3 GCN layers, logits, softmax, top2, routing ----
__global__ __launch_bounds__(256) void k_gate(const float* hs, const float* Wmlp,
        const float* convW, const float* wproj, const float* Ahat, const float* expg,
        float* out, int* cnt, int* toklist, float* wlist) {
    int t = blockIdx.x, g = threadIdx.x;
    __shared__ float xt[Dm];
    __shared__ float node[Nc][DGc];
    __shared__ float A[Nc * Nc];
    __shared__ float wp[DGc];
    __shared__ float red[4][Ec];

#pragma unroll
    for (int i = 0; i < 4; i++) xt[i * 256 + g] = hs[(size_t)t * Dm + i * 256 + g];
    if (g < Nc * Nc) A[g] = Ahat[g];
    wp[g] = wproj[g];
#pragma unroll
    for (int n = 0; n < Ec; n++) node[n][g] = expg[n * DGc + g];
    __syncthreads();

    // xg = silu(x @ W_mlp), column g
    float a0 = 0.f, a1 = 0.f, a2 = 0.f, a3 = 0.f;
    for (int k = 0; k < Dm; k += 4) {
        a0 += xt[k]     * Wmlp[(k)     * DGc + g];
        a1 += xt[k + 1] * Wmlp[(k + 1) * DGc + g];
        a2 += xt[k + 2] * Wmlp[(k + 2) * DGc + g];
        a3 += xt[k + 3] * Wmlp[(k + 3) * DGc + g];
    }
    node[8][g] = silu_f((a0 + a1) + (a2 + a3));
    __syncthreads();

    // GCN layers: tmp = node @ convW[l]; node = silu(A_hat @ tmp)
    for (int l = 0; l < Lc; l++) {
        const float* W = convW + (size_t)l * DGc * DGc;
        float acc[Nc];
#pragma unroll
        for (int n = 0; n < Nc; n++) acc[n] = 0.f;
        for (int k = 0; k < DGc; k++) {
            float w = W[k * DGc + g];
#pragma unroll
            for (int n = 0; n < Nc; n++) acc[n] += node[n][k] * w;
        }
        float nn2[Nc];
#pragma unroll
        for (int n = 0; n < Nc; n++) {
            float s = 0.f;
#pragma unroll
            for (int m = 0; m < Nc; m++) s += A[n * Nc + m] * acc[m];
            nn2[n] = silu_f(s);
        }
        __syncthreads();
#pragma unroll
        for (int n = 0; n < Nc; n++) node[n][g] = nn2[n];
        __syncthreads();
    }

    // logits: dot(node[e], wproj) via wave + block reduce
    float p[Ec];
#pragma unroll
    for (int e = 0; e < Ec; e++) p[e] = node[e][g] * wp[g];
#pragma unroll
    for (int off = 32; off >= 1; off >>= 1) {
#pragma unroll
        for (int e = 0; e < Ec; e++) p[e] += __shfl_down(p[e], off);
    }
    int lane = g & 63, wid = g >> 6;
    if (lane == 0) {
#pragma unroll
        for (int e = 0; e < Ec; e++) red[wid][e] = p[e];
    }
    __syncthreads();
    if (g == 0) {
        float lg[Ec], mx = -1e30f;
#pragma unroll
        for (int e = 0; e < Ec; e++) {
            lg[e] = red[0][e] + red[1][e] + red[2][e] + red[3][e];
            mx = fmaxf(mx, lg[e]);
        }
        float pr[Ec], s = 0.f;
#pragma unroll
        for (int e = 0; e < Ec; e++) { pr[e] = __expf(lg[e] - mx); s += pr[e]; }
        float inv = 1.f / s;
        float* lrow = out + (size_t)TT * Dm + (size_t)t * Ec;
#pragma unroll
        for (int e = 0; e < Ec; e++) { pr[e] *= inv; lrow[e] = pr[e]; }
        // top-2 (first index wins ties, matching lax.top_k)
        int i0 = 0; float v0 = pr[0];
#pragma unroll
        for (int e = 1; e < Ec; e++) if (pr[e] > v0) { v0 = pr[e]; i0 = e; }
        int i1 = -1; float v1 = -1e30f;
#pragma unroll
        for (int e = 0; e < Ec; e++) if (e != i0 && pr[e] > v1) { v1 = pr[e]; i1 = e; }
        float* rowT = out + (size_t)TT * Dm + (size_t)TT * Ec;
        atomicAdd(&rowT[i0], 2.f * v0);
        atomicAdd(&rowT[i1], 2.f * v1);
        float winv = 1.f / (v0 + v1);
        int p0 = atomicAdd(&cnt[i0], 1);
        toklist[i0 * TT + p0] = t; wlist[i0 * TT + p0] = v0 * winv;
        int p1 = atomicAdd(&cnt[i1], 1);
        toklist[i1 * TT + p1] = t; wlist[i1 * TT + p1] = v1 * winv;
    }
}

// ---- prefix offsets over expert counts ----
__global__ void k_offs(const int* cnt, int* offs) {
    if (threadIdx.x == 0) {
        int s = 0;
        for (int e = 0; e < Ec; e++) { offs[e] = s; s += cnt[e]; }
        offs[Ec] = s;
    }
}

// ---- up-proj: h[slot] = silu(x[tok] @ W1[e])  tile: 32 tokens x 256 H cols ----
__global__ __launch_bounds__(256) void k_up(const float* hs, const float* W1,
        const int* cnt, const int* offs, const int* toklist, float* hbuf) {
    int e = blockIdx.z;
    int ne = cnt[e];
    int t0 = blockIdx.x * 32;
    if (t0 >= ne) return;
    int hc0 = blockIdx.y * 256;
    const float* W = W1 + (size_t)e * Dm * Hc;
    int tid = threadIdx.x;
    int tx = tid & 15, ty = tid >> 4;

    __shared__ float Xs[32][36];
    __shared__ float Ws[32][256];

    float4 acc0[4], acc1[4];
#pragma unroll
    for (int j = 0; j < 4; j++) { acc0[j] = make_float4(0,0,0,0); acc1[j] = make_float4(0,0,0,0); }

    int lr = tid >> 3;          // row 0..31 for X loads
    int lk = (tid & 7) * 4;     // k sub-offset
    int ltok = (t0 + lr < ne) ? toklist[e * TT + t0 + lr] : -1;

    for (int kb = 0; kb < Dm; kb += 32) {
        float4 xv = make_float4(0, 0, 0, 0);
        if (ltok >= 0) xv = *(const float4*)&hs[(size_t)ltok * Dm + kb + lk];
        *(float4*)&Xs[lr][lk] = xv;
#pragma unroll 4
        for (int i = 0; i < 32; i++)
            Ws[i][tid] = W[(size_t)(kb + i) * Hc + hc0 + tid];
        __syncthreads();
#pragma unroll
        for (int kk = 0; kk < 32; kk++) {
            float a0 = Xs[ty][kk], a1 = Xs[ty + 16][kk];
#pragma unroll
            for (int j = 0; j < 4; j++) {
                float4 b = *(const float4*)&Ws[kk][j * 64 + tx * 4];
                acc0[j].x += a0 * b.x; acc0[j].y += a0 * b.y; acc0[j].z += a0 * b.z; acc0[j].w += a0 * b.w;
                acc1[j].x += a1 * b.x; acc1[j].y += a1 * b.y; acc1[j].z += a1 * b.z; acc1[j].w += a1 * b.w;
            }
        }
        __syncthreads();
    }
    int base = offs[e];
    if (t0 + ty < ne) {
        size_t row = (size_t)(base + t0 + ty) * Hc + hc0;
#pragma unroll
        for (int j = 0; j < 4; j++) {
            float4 v = acc0[j];
            v.x = silu_f(v.x); v.y = silu_f(v.y); v.z = silu_f(v.z); v.w = silu_f(v.w);
            *(float4*)&hbuf[row + j * 64 + tx * 4] = v;
        }
    }
    if (t0 + ty + 16 < ne) {
        size_t row = (size_t)(base + t0 + ty + 16) * Hc + hc0;
#pragma unroll
        for (int j = 0; j < 4; j++) {
            float4 v = acc1[j];
            v.x = silu_f(v.x); v.y = silu_f(v.y); v.z = silu_f(v.z); v.w = silu_f(v.w);
            *(float4*)&hbuf[row + j * 64 + tx * 4] = v;
        }
    }
}

// ---- down-proj: final[tok] += w * (h[slot] @ W2[e])  tile: 32 tokens x 256 D cols ----
__global__ __launch_bounds__(256) void k_down(const float* hbuf, const float* W2,
        const int* cnt, const int* offs, const int* toklist, const float* wlist,
        float* out) {
    int e = blockIdx.z;
    int ne = cnt[e];
    int t0 = blockIdx.x * 32;
    if (t0 >= ne) return;
    int dc0 = blockIdx.y * 256;
    const float* W = W2 + (size_t)e * Hc * Dm;
    int base = offs[e];
    int tid = threadIdx.x;
    int tx = tid & 15, ty = tid >> 4;

    __shared__ float Xs[32][36];
    __shared__ float Ws[32][256];

    float4 acc0[4], acc1[4];
#pragma unroll
    for (int j = 0; j < 4; j++) { acc0[j] = make_float4(0,0,0,0); acc1[j] = make_float4(0,0,0,0); }

    int lr = tid >> 3;
    int lk = (tid & 7) * 4;
    bool lval = (t0 + lr < ne);

    for (int kb = 0; kb < Hc; kb += 32) {
        float4 xv = make_float4(0, 0, 0, 0);
        if (lval) xv = *(const float4*)&hbuf[(size_t)(base + t0 + lr) * Hc + kb + lk];
        *(float4*)&Xs[lr][lk] = xv;
#pragma unroll 4
        for (int i = 0; i < 32; i++)
            Ws[i][tid] = W[(size_t)(kb + i) * Dm + dc0 + tid];
        __syncthreads();
#pragma unroll
        for (int kk = 0; kk < 32; kk++) {
            float a0 = Xs[ty][kk], a1 = Xs[ty + 16][kk];
#pragma unroll
            for (int j = 0; j < 4; j++) {
                float4 b = *(const float4*)&Ws[kk][j * 64 + tx * 4];
                acc0[j].x += a0 * b.x; acc0[j].y += a0 * b.y; acc0[j].z += a0 * b.z; acc0[j].w += a0 * b.w;
                acc1[j].x += a1 * b.x; acc1[j].y += a1 * b.y; acc1[j].z += a1 * b.z; acc1[j].w += a1 * b.w;
            }
        }
        __syncthreads();
    }
    if (t0 + ty < ne) {
        int tok = toklist[e * TT + t0 + ty];
        float w = wlist[e * TT + t0 + ty];
        float* dst = out + (size_t)tok * Dm + dc0;
#pragma unroll
        for (int j = 0; j < 4; j++) {
            atomicAdd(&dst[j * 64 + tx * 4 + 0], w * acc0[j].x);
            atomicAdd(&dst[j * 64 + tx * 4 + 1], w * acc0[j].y);
            atomicAdd(&dst[j * 64 + tx * 4 + 2], w * acc0[j].z);
            atomicAdd(&dst[j * 64 + tx * 4 + 3], w * acc0[j].w);
        }
    }
    if (t0 + ty + 16 < ne) {
        int tok = toklist[e * TT + t0 + ty + 16];
        float w = wlist[e * TT + t0 + ty + 16];
        float* dst = out + (size_t)tok * Dm + dc0;
#pragma unroll
        for (int j = 0; j < 4; j++) {
            atomicAdd(&dst[j * 64 + tx * 4 + 0], w * acc1[j].x);
            atomicAdd(&dst[j * 64 + tx * 4 + 1], w * acc1[j].y);
            atomicAdd(&dst[j * 64 + tx * 4 + 2], w * acc1[j].z);
            atomicAdd(&dst[j * 64 + tx * 4 + 3], w * acc1[j].w);
        }
    }
}

extern "C" void kernel_launch(void* const* d_in, const int* in_sizes, int n_in,
                              void* d_out, int out_size, void* d_ws, size_t ws_size,
                              hipStream_t stream) {
    const float* hs    = (const float*)d_in[0];
    const float* X     = (const float*)d_in[1];
    const float* Wmlp  = (const float*)d_in[2];
    const float* Wst   = (const float*)d_in[3];
    const float* convW = (const float*)d_in[4];
    const float* wproj = (const float*)d_in[5];
    const float* W1    = (const float*)d_in[6];
    const float* W2    = (const float*)d_in[7];
    const float* lamb  = (const float*)d_in[8];
    const float* theta = (const float*)d_in[9];
    const float* count = (const float*)d_in[10];
    const float* Ahat  = (const float*)d_in[11];
    float* out = (float*)d_out;
    char* ws = (char*)d_ws;

    float* expg    = (float*)ws;                       // 8 KB
    int*   cnt     = (int*)(ws + 8192);                // 32 B
    int*   offs    = (int*)(ws + 8192 + 128);          // 36 B
    int*   toklist = (int*)(ws + 16384);               // 64 KB
    float* wlist   = (float*)(ws + 16384 + 65536);     // 64 KB
    float* hbuf    = (float*)(ws + 16384 + 131072);    // 4096*2048 f32 = 33.5 MB

    hipMemsetAsync(d_out, 0, (size_t)TT * Dm * sizeof(float), stream);
    k_init<<<1, 64, 0, stream>>>(count, lamb, theta, out, cnt);
    k_expg<<<1, 256, 0, stream>>>(X, Wst, expg);
    k_gate<<<TT, 256, 0, stream>>>(hs, Wmlp, convW, wproj, Ahat, expg,
                                   out, cnt, toklist, wlist);
    k_offs<<<1, 1, 0, stream>>>(cnt, offs);
    k_up<<<dim3(64, Hc / 256, Ec), 256, 0, stream>>>(hs, W1, cnt, offs, toklist, hbuf);
    k_down<<<dim3(64, Dm / 256, Ec), 256, 0, stream>>>(hbuf, W2, cnt, offs, toklist, wlist, out);
}

// Round 2
// 481.677 us; speedup vs baseline: 3.1657x; 3.1657x over previous
//
#include <hip/hip_runtime.h>
#include <math.h>

#define TT 2048   // tokens
#define Dm 1024   // model dim
#define DGc 256   // gate dim
#define Ec 8      // experts
#define Nc 9      // graph nodes
#define Lc 3      // GCN layers
#define Hc 2048   // FFN hidden
#define PADMAX 5120
#define NTILE_MAX 40

typedef __attribute__((ext_vector_type(8))) short short8v;
typedef __attribute__((ext_vector_type(4))) float f32x4;

typedef __attribute__((address_space(1))) const void gvoid;
typedef __attribute__((address_space(3))) void svoid;

__device__ __forceinline__ void gll16(const void* g, void* l) {
    __builtin_amdgcn_global_load_lds((gvoid*)g, (svoid*)l, 16, 0, 0);
}

__device__ __forceinline__ float silu_f(float x) { return x / (1.f + __expf(-x)); }

__device__ __forceinline__ unsigned short bf16_rne(float f) {
    union { float f; unsigned u; } u; u.f = f;
    return (unsigned short)((u.u + 0x7fffu + ((u.u >> 16) & 1u)) >> 16);
}

// ---- init: loss tail rows (count / lamb / theta) + zero expert counters ----
__global__ void k_init(const float* count, const float* lamb, const float* theta,
                       float* out, int* cnt) {
    int i = threadIdx.x;
    float* loss = out + (size_t)TT * Dm;
    if (i < Ec)            loss[(size_t)TT * Ec + i]            = count[i];
    else if (i < 2 * Ec)   loss[(size_t)(TT + 1) * Ec + (i - Ec)]   = lamb[0];
    else if (i < 3 * Ec)   loss[(size_t)(TT + 2) * Ec + (i - 2*Ec)] = theta[0];
    if (i < Ec) cnt[i] = 0;
}

// ---- expert embeddings: expg = silu(X @ W_struct)  [8,256] ----
__global__ __launch_bounds__(256) void k_expg(const float* X, const float* Wst, float* expg) {
    __shared__ float xs[Ec * Dm];
    int g = threadIdx.x;
    for (int i = 0; i < Ec * Dm / 256; i++) xs[i * 256 + g] = X[i * 256 + g];
    __syncthreads();
    float acc[Ec];
#pragma unroll
    for (int e = 0; e < Ec; e++) acc[e] = 0.f;
    for (int k = 0; k < Dm; k++) {
        float w = Wst[k * DGc + g];
#pragma unroll
        for (int e = 0; e < Ec; e++) acc[e] += xs[e * Dm + k] * w;
    }
#pragma unroll
    for (int e = 0; e < Ec; e++) expg[e * DGc + g] = silu_f(acc[e]);
}

// ---- per-token: xg, 3 GCN layers, logits, softmax, top2, routing ----
__global__ __launch_bounds__(256) void k_gate(const float* hs, const float* Wmlp,
        const float* convW, const float* wproj, const float* Ahat, const float* expg,
        float* out, int* cnt, int* toklist, float* wlist) {
    int t = blockIdx.x, g = threadIdx.x;
    __shared__ float xt[Dm];
    __shared__ float node[Nc][DGc];
    __shared__ float A[Nc * Nc];
    __shared__ float wp[DGc];
    __shared__ float red[4][Ec];

#pragma unroll
    for (int i = 0; i < 4; i++) xt[i * 256 + g] = hs[(size_t)t * Dm + i * 256 + g];
    if (g < Nc * Nc) A[g] = Ahat[g];
    wp[g] = wproj[g];
#pragma unroll
    for (int n = 0; n < Ec; n++) node[n][g] = expg[n * DGc + g];
    __syncthreads();

    float a0 = 0.f, a1 = 0.f, a2 = 0.f, a3 = 0.f;
    for (int k = 0; k < Dm; k += 4) {
        a0 += xt[k]     * Wmlp[(k)     * DGc + g];
        a1 += xt[k + 1] * Wmlp[(k + 1) * DGc + g];
        a2 += xt[k + 2] * Wmlp[(k + 2) * DGc + g];
        a3 += xt[k + 3] * Wmlp[(k + 3) * DGc + g];
    }
    node[8][g] = silu_f((a0 + a1) + (a2 + a3));
    __syncthreads();

    for (int l = 0; l < Lc; l++) {
        const float* W = convW + (size_t)l * DGc * DGc;
        float acc[Nc];
#pragma unroll
        for (int n = 0; n < Nc; n++) acc[n] = 0.f;
        for (int k = 0; k < DGc; k++) {
            float w = W[k * DGc + g];
#pragma unroll
            for (int n = 0; n < Nc; n++) acc[n] += node[n][k] * w;
        }
        float nn2[Nc];
#pragma unroll
        for (int n = 0; n < Nc; n++) {
            float s = 0.f;
#pragma unroll
            for (int m = 0; m < Nc; m++) s += A[n * Nc + m] * acc[m];
            nn2[n] = silu_f(s);
        }
        __syncthreads();
#pragma unroll
        for (int n = 0; n < Nc; n++) node[n][g] = nn2[n];
        __syncthreads();
    }

    float p[Ec];
#pragma unroll
    for (int e = 0; e < Ec; e++) p[e] = node[e][g] * wp[g];
#pragma unroll
    for (int off = 32; off >= 1; off >>= 1) {
#pragma unroll
        for (int e = 0; e < Ec; e++) p[e] += __shfl_down(p[e], off);
    }
    int lane = g & 63, wid = g >> 6;
    if (lane == 0) {
#pragma unroll
        for (int e = 0; e < Ec; e++) red[wid][e] = p[e];
    }
    __syncthreads();
    if (g == 0) {
        float lg[Ec], mx = -1e30f;
#pragma unroll
        for (int e = 0; e < Ec; e++) {
            lg[e] = red[0][e] + red[1][e] + red[2][e] + red[3][e];
            mx = fmaxf(mx, lg[e]);
        }
        float pr[Ec], s = 0.f;
#pragma unroll
        for (int e = 0; e < Ec; e++) { pr[e] = __expf(lg[e] - mx); s += pr[e]; }
        float inv = 1.f / s;
        float* lrow = out + (size_t)TT * Dm + (size_t)t * Ec;
#pragma unroll
        for (int e = 0; e < Ec; e++) { pr[e] *= inv; lrow[e] = pr[e]; }
        int i0 = 0; float v0 = pr[0];
#pragma unroll
        for (int e = 1; e < Ec; e++) if (pr[e] > v0) { v0 = pr[e]; i0 = e; }
        int i1 = -1; float v1 = -1e30f;
#pragma unroll
        for (int e = 0; e < Ec; e++) if (e != i0 && pr[e] > v1) { v1 = pr[e]; i1 = e; }
        float* rowT = out + (size_t)TT * Dm + (size_t)TT * Ec;
        atomicAdd(&rowT[i0], 2.f * v0);
        atomicAdd(&rowT[i1], 2.f * v1);
        float winv = 1.f / (v0 + v1);
        int p0 = atomicAdd(&cnt[i0], 1);
        toklist[i0 * TT + p0] = t; wlist[i0 * TT + p0] = v0 * winv;
        int p1 = atomicAdd(&cnt[i1], 1);
        toklist[i1 * TT + p1] = t; wlist[i1 * TT + p1] = v1 * winv;
    }
}

// ---- padded offsets + tile map (tiles of 128 slots, each within one expert) ----
__global__ void k_offs(const int* cnt, int* poffs, int* tile_e, int* tile_m0) {
    if (threadIdx.x == 0) {
        int pad = 0, nt = 0;
        for (int e = 0; e < Ec; e++) {
            poffs[e] = pad;
            int te = (cnt[e] + 127) >> 7;
            for (int i = 0; i < te; i++) { tile_e[nt] = e; tile_m0[nt] = pad + i * 128; nt++; }
            pad += te * 128;
        }
        poffs[Ec] = pad;
        for (; nt < NTILE_MAX; nt++) { tile_e[nt] = -1; tile_m0[nt] = 0; }
    }
}

// ---- transpose + cast: src [R][C] f32 per expert -> dst [C][R] bf16 per expert ----
__global__ __launch_bounds__(256) void k_tcast(const float* src, unsigned short* dst,
                                               int R, int C) {
    int e = blockIdx.z;
    int c0 = blockIdx.x * 32, r0 = blockIdx.y * 32;
    const float* S = src + (size_t)e * R * C;
    unsigned short* Dq = dst + (size_t)e * R * C;
    __shared__ float t[32][33];
    int tid = threadIdx.x;
    int j = tid & 31, i4 = tid >> 5;
#pragma unroll
    for (int r = 0; r < 4; r++)
        t[i4 * 4 + r][j] = S[(size_t)(r0 + i4 * 4 + r) * C + c0 + j];
    __syncthreads();
    int ci = tid >> 3;
    int r4 = (tid & 7) * 4;
    ushort4 v;
    v.x = bf16_rne(t[r4 + 0][ci]);
    v.y = bf16_rne(t[r4 + 1][ci]);
    v.z = bf16_rne(t[r4 + 2][ci]);
    v.w = bf16_rne(t[r4 + 3][ci]);
    *(ushort4*)&Dq[(size_t)(c0 + ci) * R + r0 + r4] = v;
}

// ---- gather routed tokens into padded slot-major bf16 buffer + slot maps ----
__global__ __launch_bounds__(256) void k_gather(const float* hs, const int* cnt,
        const int* poffs, const int* toklist, const float* wlist,
        unsigned short* xb, int* tokslot, float* wslot) {
    int tid = threadIdx.x;
    int s = blockIdx.x * 2 + (tid >> 7);
    int j = (tid & 127) * 8;
    int e = 0;
#pragma unroll
    for (int q = 1; q < Ec; q++) if (s >= poffs[q]) e = q;
    int pos = s - poffs[e];
    int tok = -1; float w = 0.f;
    if (pos < cnt[e]) { tok = toklist[e * TT + pos]; w = wlist[e * TT + pos]; }
    if (j == 0) { tokslot[s] = tok; wslot[s] = w; }
    ushort4 o0, o1;
    if (tok >= 0) {
        const float* xr = hs + (size_t)tok * Dm + j;
        o0.x = bf16_rne(xr[0]); o0.y = bf16_rne(xr[1]); o0.z = bf16_rne(xr[2]); o0.w = bf16_rne(xr[3]);
        o1.x = bf16_rne(xr[4]); o1.y = bf16_rne(xr[5]); o1.z = bf16_rne(xr[6]); o1.w = bf16_rne(xr[7]);
    } else {
        o0 = make_ushort4(0, 0, 0, 0); o1 = o0;
    }
    *(ushort4*)&xb[(size_t)s * Dm + j] = o0;
    *(ushort4*)&xb[(size_t)s * Dm + j + 4] = o1;
}

// ---- MFMA grouped GEMM, 128x128 tile, BK=32, 4 waves x (4x4) 16x16x32 frags ----
// MODE 0: C = silu(A @ B^T) -> bf16 out [PADMAX][NDIM]
// MODE 1: out[tok] += wslot * (A @ B^T)  (fp32 atomics)
template<int KDIM, int NDIM, int MODE>
__global__ __launch_bounds__(256) void k_mfma(const unsigned short* Abuf,
        const unsigned short* Wt, const int* tile_e, const int* tile_m0,
        const int* tokslot, const float* wslot, void* outp) {
    int e = tile_e[blockIdx.x];
    if (e < 0) return;
    int m0 = tile_m0[blockIdx.x];
    int n0 = blockIdx.y * 128;
    const unsigned short* Bg = Wt + (size_t)e * NDIM * KDIM;   // [NDIM][KDIM]
    __shared__ __align__(16) unsigned short As[128 * 32];
    __shared__ __align__(16) unsigned short Bs[128 * 32];
    int tid = threadIdx.x;
    int lane = tid & 63;
    int wid = tid >> 6;
    int wr = wid >> 1, wc = wid & 1;
    int lo = lane & 15, hi = lane >> 4;

    f32x4 acc[4][4];
#pragma unroll
    for (int m = 0; m < 4; m++)
#pragma unroll
        for (int n = 0; n < 4; n++) acc[m][n] = (f32x4)(0.f);

    int arow = tid >> 2;
    int acol = (tid & 3) * 8;
    const unsigned short* Ag = Abuf + (size_t)m0 * KDIM;
    const unsigned short* Bt = Bg + (size_t)n0 * KDIM;

    for (int kb = 0; kb < KDIM; kb += 32) {
        gll16(Ag + (size_t)arow * KDIM + kb + acol,        (char*)As + tid * 16);
        gll16(Ag + (size_t)(arow + 64) * KDIM + kb + acol, (char*)As + 4096 + tid * 16);
        gll16(Bt + (size_t)arow * KDIM + kb + acol,        (char*)Bs + tid * 16);
        gll16(Bt + (size_t)(arow + 64) * KDIM + kb + acol, (char*)Bs + 4096 + tid * 16);
        __syncthreads();
        short8v a[4], b[4];
#pragma unroll
        for (int m = 0; m < 4; m++)
            a[m] = *(const short8v*)&As[(wr * 64 + m * 16 + lo) * 32 + hi * 8];
#pragma unroll
        for (int n = 0; n < 4; n++)
            b[n] = *(const short8v*)&Bs[(wc * 64 + n * 16 + lo) * 32 + hi * 8];
#pragma unroll
        for (int m = 0; m < 4; m++)
#pragma unroll
            for (int n = 0; n < 4; n++)
                acc[m][n] = __builtin_amdgcn_mfma_f32_16x16x32_bf16(a[m], b[n], acc[m][n], 0, 0, 0);
        __syncthreads();
    }

    if (MODE == 0) {
        unsigned short* O = (unsigned short*)outp;
#pragma unroll
        for (int m = 0; m < 4; m++) {
#pragma unroll
            for (int n = 0; n < 4; n++) {
                int col = n0 + wc * 64 + n * 16 + lo;
#pragma unroll
                for (int r = 0; r < 4; r++) {
                    int row = m0 + wr * 64 + m * 16 + hi * 4 + r;
                    O[(size_t)row * NDIM + col] = bf16_rne(silu_f(acc[m][n][r]));
                }
            }
        }
    } else {
        float* O = (float*)outp;
#pragma unroll
        for (int m = 0; m < 4; m++) {
            int toks[4]; float ws[4];
#pragma unroll
            for (int r = 0; r < 4; r++) {
                int row = m0 + wr * 64 + m * 16 + hi * 4 + r;
                toks[r] = tokslot[row];
                ws[r] = wslot[row];
            }
#pragma unroll
            for (int n = 0; n < 4; n++) {
                int col = n0 + wc * 64 + n * 16 + lo;
#pragma unroll
                for (int r = 0; r < 4; r++) {
                    if (toks[r] >= 0)
                        atomicAdd(&O[(size_t)toks[r] * Dm + col], ws[r] * acc[m][n][r]);
                }
            }
        }
    }
}

extern "C" void kernel_launch(void* const* d_in, const int* in_sizes, int n_in,
                              void* d_out, int out_size, void* d_ws, size_t ws_size,
                              hipStream_t stream) {
    const float* hs    = (const float*)d_in[0];
    const float* X     = (const float*)d_in[1];
    const float* Wmlp  = (const float*)d_in[2];
    const float* Wst   = (const float*)d_in[3];
    const float* convW = (const float*)d_in[4];
    const float* wproj = (const float*)d_in[5];
    const float* W1    = (const float*)d_in[6];
    const float* W2    = (const float*)d_in[7];
    const float* lamb  = (const float*)d_in[8];
    const float* theta = (const float*)d_in[9];
    const float* count = (const float*)d_in[10];
    const float* Ahat  = (const float*)d_in[11];
    float* out = (float*)d_out;
    char* ws = (char*)d_ws;

    float*          expg    = (float*)ws;                       // [0, 8K)
    int*            cnt     = (int*)(ws + 8192);
    int*            poffs   = (int*)(ws + 8448);
    int*            tile_e  = (int*)(ws + 8704);
    int*            tile_m0 = (int*)(ws + 8960);
    int*            toklist = (int*)(ws + 16384);               // 64 KB
    float*          wlist   = (float*)(ws + 81920);             // 64 KB
    int*            tokslot = (int*)(ws + 147456);              // 20 KB
    float*          wslot   = (float*)(ws + 167936);            // 20 KB
    unsigned short* xb      = (unsigned short*)(ws + 188416);   // 10.5 MB
    unsigned short* W1T     = (unsigned short*)(ws + 10674176); // 33.5 MB
    unsigned short* W2T     = (unsigned short*)(ws + 44228608); // 33.5 MB
    unsigned short* hb      = (unsigned short*)(ws + 77783040); // 21 MB  (end ~98.8 MB)

    k_init<<<1, 64, 0, stream>>>(count, lamb, theta, out, cnt);
    k_expg<<<1, 256, 0, stream>>>(X, Wst, expg);
    k_tcast<<<dim3(Hc / 32, Dm / 32, Ec), 256, 0, stream>>>(W1, W1T, Dm, Hc);
    k_tcast<<<dim3(Dm / 32, Hc / 32, Ec), 256, 0, stream>>>(W2, W2T, Hc, Dm);
    k_gate<<<TT, 256, 0, stream>>>(hs, Wmlp, convW, wproj, Ahat, expg,
                                   out, cnt, toklist, wlist);
    k_offs<<<1, 1, 0, stream>>>(cnt, poffs, tile_e, tile_m0);
    k_gather<<<PADMAX / 2, 256, 0, stream>>>(hs, cnt, poffs, toklist, wlist,
                                             xb, tokslot, wslot);
    hipMemsetAsync(d_out, 0, (size_t)TT * Dm * sizeof(float), stream);
    k_mfma<Dm, Hc, 0><<<dim3(NTILE_MAX, Hc / 128), 256, 0, stream>>>(
        xb, W1T, tile_e, tile_m0, tokslot, wslot, hb);
    k_mfma<Hc, Dm, 1><<<dim3(NTILE_MAX, Dm / 128), 256, 0, stream>>>(
        hb, W2T, tile_e, tile_m0, tokslot, wslot, out);
}

// Round 3
// 402.491 us; speedup vs baseline: 3.7885x; 1.1967x over previous
//
#include <hip/hip_runtime.h>
#include <math.h>

#define TT 2048   // tokens
#define Dm 1024   // model dim
#define DGc 256   // gate dim
#define Ec 8      // experts
#define Nc 9      // graph nodes
#define Hc 2048   // FFN hidden
#define PADMAX 5120
#define NTILE_MAX 40

typedef __attribute__((ext_vector_type(8))) short short8v;
typedef __attribute__((ext_vector_type(4))) float f32x4;

typedef __attribute__((address_space(1))) const void gvoid;
typedef __attribute__((address_space(3))) void svoid;

__device__ __forceinline__ void gll16(const void* g, void* l) {
    __builtin_amdgcn_global_load_lds((gvoid*)g, (svoid*)l, 16, 0, 0);
}

__device__ __forceinline__ float silu_f(float x) { return x / (1.f + __expf(-x)); }

__device__ __forceinline__ unsigned short bf16_rne(float f) {
    union { float f; unsigned u; } u; u.f = f;
    return (unsigned short)((u.u + 0x7fffu + ((u.u >> 16) & 1u)) >> 16);
}
__device__ __forceinline__ float bf16_to_f(unsigned short h) {
    union { unsigned u; float f; } u; u.u = ((unsigned)h) << 16; return u.f;
}
__device__ __forceinline__ void split2(float x, unsigned short& h, unsigned short& l) {
    h = bf16_rne(x);
    l = bf16_rne(x - bf16_to_f(h));
}

// ---- init: loss tail rows (count / lamb / theta) + zero expert counters ----
__global__ void k_init(const float* count, const float* lamb, const float* theta,
                       float* out, int* cnt) {
    int i = threadIdx.x;
    float* loss = out + (size_t)TT * Dm;
    if (i < Ec)            loss[(size_t)TT * Ec + i]            = count[i];
    else if (i < 2 * Ec)   loss[(size_t)(TT + 1) * Ec + (i - Ec)]   = lamb[0];
    else if (i < 3 * Ec)   loss[(size_t)(TT + 2) * Ec + (i - 2*Ec)] = theta[0];
    if (i < Ec) cnt[i] = 0;
}

// ---- split hs fp32 -> hi/lo bf16 (row-major, K-contig) ----
__global__ __launch_bounds__(256) void k_split(const float* src,
        unsigned short* dh, unsigned short* dl) {
    size_t i = ((size_t)blockIdx.x * 256 + threadIdx.x) * 8;
    float4 v0 = *(const float4*)&src[i];
    float4 v1 = *(const float4*)&src[i + 4];
    ushort4 h0, l0, h1, l1;
    split2(v0.x, h0.x, l0.x); split2(v0.y, h0.y, l0.y);
    split2(v0.z, h0.z, l0.z); split2(v0.w, h0.w, l0.w);
    split2(v1.x, h1.x, l1.x); split2(v1.y, h1.y, l1.y);
    split2(v1.z, h1.z, l1.z); split2(v1.w, h1.w, l1.w);
    *(ushort4*)&dh[i] = h0; *(ushort4*)&dh[i + 4] = h1;
    *(ushort4*)&dl[i] = l0; *(ushort4*)&dl[i + 4] = l1;
}

// ---- transpose+split: src[e][R][C] f32 -> dh/dl [e][C][R] bf16 ----
__global__ __launch_bounds__(256) void k_tsplit(const float* src,
        unsigned short* dh, unsigned short* dl, int R, int C) {
    int e = blockIdx.z;
    int c0 = blockIdx.x * 32, r0 = blockIdx.y * 32;
    const float* S = src + (size_t)e * R * C;
    __shared__ float t[32][36];
    int tid = threadIdx.x;
    int i = tid >> 3, j4 = (tid & 7) * 4;
    *(float4*)&t[i][j4] = *(const float4*)&S[(size_t)(r0 + i) * C + c0 + j4];
    __syncthreads();
    int ci = tid >> 3, r4 = (tid & 7) * 4;
    ushort4 h, l;
    split2(t[r4 + 0][ci], h.x, l.x);
    split2(t[r4 + 1][ci], h.y, l.y);
    split2(t[r4 + 2][ci], h.z, l.z);
    split2(t[r4 + 3][ci], h.w, l.w);
    size_t o = (size_t)e * R * C + (size_t)(c0 + ci) * R + r0 + r4;
    *(ushort4*)&dh[o] = h;
    *(ushort4*)&dl[o] = l;
}

// ---- transpose + cast (hi only, FFN weights) ----
__global__ __launch_bounds__(256) void k_tcast(const float* src, unsigned short* dst,
                                               int R, int C) {
    int e = blockIdx.z;
    int c0 = blockIdx.x * 32, r0 = blockIdx.y * 32;
    const float* S = src + (size_t)e * R * C;
    unsigned short* Dq = dst + (size_t)e * R * C;
    __shared__ float t[32][36];
    int tid = threadIdx.x;
    int i = tid >> 3, j4 = (tid & 7) * 4;
    *(float4*)&t[i][j4] = *(const float4*)&S[(size_t)(r0 + i) * C + c0 + j4];
    __syncthreads();
    int ci = tid >> 3, r4 = (tid & 7) * 4;
    ushort4 v;
    v.x = bf16_rne(t[r4 + 0][ci]);
    v.y = bf16_rne(t[r4 + 1][ci]);
    v.z = bf16_rne(t[r4 + 2][ci]);
    v.w = bf16_rne(t[r4 + 3][ci]);
    *(ushort4*)&Dq[(size_t)(c0 + ci) * R + r0 + r4] = v;
}

// ---- expert embeddings: expg = silu(X @ W_struct)  [8,256] ----
__global__ __launch_bounds__(256) void k_expg(const float* X, const float* Wst, float* expg) {
    __shared__ float xs[Ec * Dm];
    int g = threadIdx.x;
    for (int i = 0; i < Ec * Dm / 256; i++) xs[i * 256 + g] = X[i * 256 + g];
    __syncthreads();
    float acc[Ec];
#pragma unroll
    for (int e = 0; e < Ec; e++) acc[e] = 0.f;
    for (int k = 0; k < Dm; k++) {
        float w = Wst[k * DGc + g];
#pragma unroll
        for (int e = 0; e < Ec; e++) acc[e] += xs[e * Dm + k] * w;
    }
#pragma unroll
    for (int e = 0; e < Ec; e++) expg[e * DGc + g] = silu_f(acc[e]);
}

// ---- S1[n] = sum_{m<8} A[n,m] * (expg @ W0)[m]   [9,256] fp32 ----
__global__ __launch_bounds__(256) void k_s1(const float* expg, const float* W0,
                                            const float* Ahat, float* S1) {
    __shared__ float eg[Ec * DGc];
    int g = threadIdx.x;
#pragma unroll
    for (int i = 0; i < Ec; i++) eg[i * DGc + g] = expg[i * DGc + g];
    __syncthreads();
    float G[Ec];
#pragma unroll
    for (int m = 0; m < Ec; m++) G[m] = 0.f;
    for (int k = 0; k < DGc; k++) {
        float w = W0[k * DGc + g];
#pragma unroll
        for (int m = 0; m < Ec; m++) G[m] += eg[m * DGc + k] * w;
    }
#pragma unroll
    for (int n = 0; n < Nc; n++) {
        float s = 0.f;
#pragma unroll
        for (int m = 0; m < Ec; m++) s += Ahat[n * Nc + m] * G[m];
        S1[n * DGc + g] = s;
    }
}

// ---- split-bf16 4-pass MFMA GEMM: C[M,256] = A[M,K] @ B^T (B:[256,K]) ----
// EPI 0: write fp32 C.  EPI 1: silu then split-write Oh/Ol bf16.
template<int BM, int KD, int EPI>
__global__ __launch_bounds__(256) void gemm4s(const unsigned short* Ah,
        const unsigned short* Al, const unsigned short* Bh, const unsigned short* Bl,
        float* Cf, unsigned short* Oh, unsigned short* Ol) {
    constexpr int FM = BM / 32;
    constexpr int AR = BM / 64;
    int m0 = blockIdx.x * BM, n0 = blockIdx.y * 128;
    __shared__ __align__(16) unsigned short AsH[BM * 32];
    __shared__ __align__(16) unsigned short AsL[BM * 32];
    __shared__ __align__(16) unsigned short BsH[128 * 32];
    __shared__ __align__(16) unsigned short BsL[128 * 32];
    int tid = threadIdx.x, lane = tid & 63, wid = tid >> 6;
    int wr = wid >> 1, wc = wid & 1, lo = lane & 15, hi = lane >> 4;

    f32x4 acc[FM][4];
#pragma unroll
    for (int m = 0; m < FM; m++)
#pragma unroll
        for (int n = 0; n < 4; n++) acc[m][n] = (f32x4)(0.f);

    size_t aoff = (size_t)(m0 + (tid >> 2)) * KD + (tid & 3) * 8;
    size_t boff = (size_t)(n0 + (tid >> 2)) * KD + (tid & 3) * 8;

    for (int kb = 0; kb < KD; kb += 32) {
#pragma unroll
        for (int r = 0; r < AR; r++) {
            gll16(Ah + aoff + (size_t)r * 64 * KD + kb, (char*)AsH + r * 4096 + tid * 16);
            gll16(Al + aoff + (size_t)r * 64 * KD + kb, (char*)AsL + r * 4096 + tid * 16);
        }
#pragma unroll
        for (int r = 0; r < 2; r++) {
            gll16(Bh + boff + (size_t)r * 64 * KD + kb, (char*)BsH + r * 4096 + tid * 16);
            gll16(Bl + boff + (size_t)r * 64 * KD + kb, (char*)BsL + r * 4096 + tid * 16);
        }
        __syncthreads();
        short8v ah[FM], al[FM], bh[4], bl[4];
#pragma unroll
        for (int m = 0; m < FM; m++) {
            ah[m] = *(const short8v*)&AsH[(wr * (BM / 2) + m * 16 + lo) * 32 + hi * 8];
            al[m] = *(const short8v*)&AsL[(wr * (BM / 2) + m * 16 + lo) * 32 + hi * 8];
        }
#pragma unroll
        for (int n = 0; n < 4; n++) {
            bh[n] = *(const short8v*)&BsH[(wc * 64 + n * 16 + lo) * 32 + hi * 8];
            bl[n] = *(const short8v*)&BsL[(wc * 64 + n * 16 + lo) * 32 + hi * 8];
        }
#pragma unroll
        for (int m = 0; m < FM; m++)
#pragma unroll
            for (int n = 0; n < 4; n++)
                acc[m][n] = __builtin_amdgcn_mfma_f32_16x16x32_bf16(ah[m], bh[n], acc[m][n], 0, 0, 0);
#pragma unroll
        for (int m = 0; m < FM; m++)
#pragma unroll
            for (int n = 0; n < 4; n++)
                acc[m][n] = __builtin_amdgcn_mfma_f32_16x16x32_bf16(ah[m], bl[n], acc[m][n], 0, 0, 0);
#pragma unroll
        for (int m = 0; m < FM; m++)
#pragma unroll
            for (int n = 0; n < 4; n++)
                acc[m][n] = __builtin_amdgcn_mfma_f32_16x16x32_bf16(al[m], bh[n], acc[m][n], 0, 0, 0);
#pragma unroll
        for (int m = 0; m < FM; m++)
#pragma unroll
            for (int n = 0; n < 4; n++)
                acc[m][n] = __builtin_amdgcn_mfma_f32_16x16x32_bf16(al[m], bl[n], acc[m][n], 0, 0, 0);
        __syncthreads();
    }

#pragma unroll
    for (int m = 0; m < FM; m++) {
#pragma unroll
        for (int n = 0; n < 4; n++) {
            int col = n0 + wc * 64 + n * 16 + lo;
#pragma unroll
            for (int r = 0; r < 4; r++) {
                int row = m0 + wr * (BM / 2) + m * 16 + hi * 4 + r;
                if (EPI == 0) {
                    Cf[(size_t)row * 256 + col] = acc[m][n][r];
                } else {
                    float s = silu_f(acc[m][n][r]);
                    unsigned short h, l;
                    split2(s, h, l);
                    Oh[(size_t)row * 256 + col] = h;
                    Ol[(size_t)row * 256 + col] = l;
                }
            }
        }
    }
}

// ---- layer-1 build: node1[t,n] = silu(S1[n] + A[n,8]*y[t]) -> hi/lo ----
__global__ __launch_bounds__(256) void k_l1(const float* y, const float* S1,
        const float* Ahat, unsigned short* nh, unsigned short* nl) {
    int t = blockIdx.x, g = threadIdx.x;
    float yv = y[(size_t)t * DGc + g];
#pragma unroll
    for (int n = 0; n < Nc; n++) {
        float c = Ahat[n * Nc + Ec];
        float s = silu_f(S1[n * DGc + g] + c * yv);
        unsigned short h, l;
        split2(s, h, l);
        size_t o = ((size_t)t * Nc + n) * DGc + g;
        nh[o] = h; nl[o] = l;
    }
}

// ---- mix: node[t,n] = silu(sum_m A[n,m] Z[t,m]) -> hi/lo ----
__global__ __launch_bounds__(256) void k_mix2(const float* Z, const float* Ahat,
        unsigned short* nh, unsigned short* nl) {
    int t = blockIdx.x, g = threadIdx.x;
    __shared__ float A[Nc * Nc];
    if (g < Nc * Nc) A[g] = Ahat[g];
    __syncthreads();
    float z[Nc];
#pragma unroll
    for (int m = 0; m < Nc; m++) z[m] = Z[((size_t)t * Nc + m) * DGc + g];
#pragma unroll
    for (int n = 0; n < Nc; n++) {
        float s = 0.f;
#pragma unroll
        for (int m = 0; m < Nc; m++) s += A[n * Nc + m] * z[m];
        s = silu_f(s);
        unsigned short h, l;
        split2(s, h, l);
        size_t o = ((size_t)t * Nc + n) * DGc + g;
        nh[o] = h; nl[o] = l;
    }
}

// ---- final mix + logits + softmax + top2 + routing (1 wave per token) ----
__global__ __launch_bounds__(256) void k_mix3(const float* Z, const float* Ahat,
        const float* wproj, float* out, int* cnt, int* toklist, float* wlist) {
    __shared__ float A[Nc * Nc];
    __shared__ float wp[DGc];
    int tid = threadIdx.x;
    if (tid < Nc * Nc) A[tid] = Ahat[tid];
    wp[tid] = wproj[tid];
    __syncthreads();
    int wid = tid >> 6, lane = tid & 63;
    int t = blockIdx.x * 4 + wid;
    float lg[Ec];
#pragma unroll
    for (int e = 0; e < Ec; e++) lg[e] = 0.f;
#pragma unroll
    for (int j = 0; j < 4; j++) {
        int g = j * 64 + lane;
        float z[Nc];
#pragma unroll
        for (int m = 0; m < Nc; m++) z[m] = Z[((size_t)t * Nc + m) * DGc + g];
#pragma unroll
        for (int e = 0; e < Ec; e++) {
            float s = 0.f;
#pragma unroll
            for (int m = 0; m < Nc; m++) s += A[e * Nc + m] * z[m];
            lg[e] += silu_f(s) * wp[g];
        }
    }
#pragma unroll
    for (int off = 32; off >= 1; off >>= 1) {
#pragma unroll
        for (int e = 0; e < Ec; e++) lg[e] += __shfl_xor(lg[e], off);
    }
    if (lane == 0) {
        float mx = -1e30f;
#pragma unroll
        for (int e = 0; e < Ec; e++) mx = fmaxf(mx, lg[e]);
        float pr[Ec], s = 0.f;
#pragma unroll
        for (int e = 0; e < Ec; e++) { pr[e] = __expf(lg[e] - mx); s += pr[e]; }
        float inv = 1.f / s;
        float* lrow = out + (size_t)TT * Dm + (size_t)t * Ec;
#pragma unroll
        for (int e = 0; e < Ec; e++) { pr[e] *= inv; lrow[e] = pr[e]; }
        int i0 = 0; float v0 = pr[0];
#pragma unroll
        for (int e = 1; e < Ec; e++) if (pr[e] > v0) { v0 = pr[e]; i0 = e; }
        int i1 = -1; float v1 = -1e30f;
#pragma unroll
        for (int e = 0; e < Ec; e++) if (e != i0 && pr[e] > v1) { v1 = pr[e]; i1 = e; }
        float* rowT = out + (size_t)TT * Dm + (size_t)TT * Ec;
        atomicAdd(&rowT[i0], 2.f * v0);
        atomicAdd(&rowT[i1], 2.f * v1);
        float winv = 1.f / (v0 + v1);
        int p0 = atomicAdd(&cnt[i0], 1);
        toklist[i0 * TT + p0] = t; wlist[i0 * TT + p0] = v0 * winv;
        int p1 = atomicAdd(&cnt[i1], 1);
        toklist[i1 * TT + p1] = t; wlist[i1 * TT + p1] = v1 * winv;
    }
}

// ---- padded offsets + tile map ----
__global__ void k_offs(const int* cnt, int* poffs, int* tile_e, int* tile_m0) {
    if (threadIdx.x == 0) {
        int pad = 0, nt = 0;
        for (int e = 0; e < Ec; e++) {
            poffs[e] = pad;
            int te = (cnt[e] + 127) >> 7;
            for (int i = 0; i < te; i++) { tile_e[nt] = e; tile_m0[nt] = pad + i * 128; nt++; }
            pad += te * 128;
        }
        poffs[Ec] = pad;
        for (; nt < NTILE_MAX; nt++) { tile_e[nt] = -1; tile_m0[nt] = 0; }
    }
}

// ---- gather routed tokens into padded slot-major bf16 buffer + slot maps ----
__global__ __launch_bounds__(256) void k_gather(const float* hs, const int* cnt,
        const int* poffs, const int* toklist, const float* wlist,
        unsigned short* xb, int* tokslot, float* wslot) {
    int tid = threadIdx.x;
    int s = blockIdx.x * 2 + (tid >> 7);
    int j = (tid & 127) * 8;
    int e = 0;
#pragma unroll
    for (int q = 1; q < Ec; q++) if (s >= poffs[q]) e = q;
    int pos = s - poffs[e];
    int tok = -1; float w = 0.f;
    if (pos < cnt[e]) { tok = toklist[e * TT + pos]; w = wlist[e * TT + pos]; }
    if (j == 0) { tokslot[s] = tok; wslot[s] = w; }
    ushort4 o0, o1;
    if (tok >= 0) {
        const float* xr = hs + (size_t)tok * Dm + j;
        o0.x = bf16_rne(xr[0]); o0.y = bf16_rne(xr[1]); o0.z = bf16_rne(xr[2]); o0.w = bf16_rne(xr[3]);
        o1.x = bf16_rne(xr[4]); o1.y = bf16_rne(xr[5]); o1.z = bf16_rne(xr[6]); o1.w = bf16_rne(xr[7]);
    } else {
        o0 = make_ushort4(0, 0, 0, 0); o1 = o0;
    }
    *(ushort4*)&xb[(size_t)s * Dm + j] = o0;
    *(ushort4*)&xb[(size_t)s * Dm + j + 4] = o1;
}

// ---- FFN MFMA grouped GEMM (unchanged from round 2) ----
template<int KDIM, int NDIM, int MODE>
__global__ __launch_bounds__(256) void k_mfma(const unsigned short* Abuf,
        const unsigned short* Wt, const int* tile_e, const int* tile_m0,
        const int* tokslot, const float* wslot, void* outp) {
    int e = tile_e[blockIdx.x];
    if (e < 0) return;
    int m0 = tile_m0[blockIdx.x];
    int n0 = blockIdx.y * 128;
    const unsigned short* Bg = Wt + (size_t)e * NDIM * KDIM;
    __shared__ __align__(16) unsigned short As[128 * 32];
    __shared__ __align__(16) unsigned short Bs[128 * 32];
    int tid = threadIdx.x;
    int lane = tid & 63;
    int wid = tid >> 6;
    int wr = wid >> 1, wc = wid & 1;
    int lo = lane & 15, hi = lane >> 4;

    f32x4 acc[4][4];
#pragma unroll
    for (int m = 0; m < 4; m++)
#pragma unroll
        for (int n = 0; n < 4; n++) acc[m][n] = (f32x4)(0.f);

    int arow = tid >> 2;
    int acol = (tid & 3) * 8;
    const unsigned short* Ag = Abuf + (size_t)m0 * KDIM;
    const unsigned short* Bt = Bg + (size_t)n0 * KDIM;

    for (int kb = 0; kb < KDIM; kb += 32) {
        gll16(Ag + (size_t)arow * KDIM + kb + acol,        (char*)As + tid * 16);
        gll16(Ag + (size_t)(arow + 64) * KDIM + kb + acol, (char*)As + 4096 + tid * 16);
        gll16(Bt + (size_t)arow * KDIM + kb + acol,        (char*)Bs + tid * 16);
        gll16(Bt + (size_t)(arow + 64) * KDIM + kb + acol, (char*)Bs + 4096 + tid * 16);
        __syncthreads();
        short8v a[4], b[4];
#pragma unroll
        for (int m = 0; m < 4; m++)
            a[m] = *(const short8v*)&As[(wr * 64 + m * 16 + lo) * 32 + hi * 8];
#pragma unroll
        for (int n = 0; n < 4; n++)
            b[n] = *(const short8v*)&Bs[(wc * 64 + n * 16 + lo) * 32 + hi * 8];
#pragma unroll
        for (int m = 0; m < 4; m++)
#pragma unroll
            for (int n = 0; n < 4; n++)
                acc[m][n] = __builtin_amdgcn_mfma_f32_16x16x32_bf16(a[m], b[n], acc[m][n], 0, 0, 0);
        __syncthreads();
    }

    if (MODE == 0) {
        unsigned short* O = (unsigned short*)outp;
#pragma unroll
        for (int m = 0; m < 4; m++) {
#pragma unroll
            for (int n = 0; n < 4; n++) {
                int col = n0 + wc * 64 + n * 16 + lo;
#pragma unroll
                for (int r = 0; r < 4; r++) {
                    int row = m0 + wr * 64 + m * 16 + hi * 4 + r;
                    O[(size_t)row * NDIM + col] = bf16_rne(silu_f(acc[m][n][r]));
                }
            }
        }
    } else {
        float* O = (float*)outp;
#pragma unroll
        for (int m = 0; m < 4; m++) {
            int toks[4]; float ws[4];
#pragma unroll
            for (int r = 0; r < 4; r++) {
                int row = m0 + wr * 64 + m * 16 + hi * 4 + r;
                toks[r] = tokslot[row];
                ws[r] = wslot[row];
            }
#pragma unroll
            for (int n = 0; n < 4; n++) {
                int col = n0 + wc * 64 + n * 16 + lo;
#pragma unroll
                for (int r = 0; r < 4; r++) {
                    if (toks[r] >= 0)
                        atomicAdd(&O[(size_t)toks[r] * Dm + col], ws[r] * acc[m][n][r]);
                }
            }
        }
    }
}

extern "C" void kernel_launch(void* const* d_in, const int* in_sizes, int n_in,
                              void* d_out, int out_size, void* d_ws, size_t ws_size,
                              hipStream_t stream) {
    const float* hs    = (const float*)d_in[0];
    const float* X     = (const float*)d_in[1];
    const float* Wmlp  = (const float*)d_in[2];
    const float* Wst   = (const float*)d_in[3];
    const float* convW = (const float*)d_in[4];
    const float* wproj = (const float*)d_in[5];
    const float* W1    = (const float*)d_in[6];
    const float* W2    = (const float*)d_in[7];
    const float* lamb  = (const float*)d_in[8];
    const float* theta = (const float*)d_in[9];
    const float* count = (const float*)d_in[10];
    const float* Ahat  = (const float*)d_in[11];
    float* out = (float*)d_out;
    char* ws = (char*)d_ws;

    // persistent layout (98.8 MB total, same footprint as round 2)
    float*          expg    = (float*)ws;
    int*            cnt     = (int*)(ws + 8192);
    int*            poffs   = (int*)(ws + 8320);
    int*            tile_e  = (int*)(ws + 8448);
    int*            tile_m0 = (int*)(ws + 8704);
    float*          S1      = (float*)(ws + 9216);
    int*            toklist = (int*)(ws + 20480);
    float*          wlist   = (float*)(ws + 86016);
    int*            tokslot = (int*)(ws + 151552);
    float*          wslot   = (float*)(ws + 172032);
    unsigned short* xb      = (unsigned short*)(ws + 196608);   // 10.5 MB
    unsigned short* W1T     = (unsigned short*)(ws + 10682368); // 33.5 MB
    unsigned short* W2T     = (unsigned short*)(ws + 44236800); // 33.5 MB
    unsigned short* hb      = (unsigned short*)(ws + 77791232); // 21 MB

    // gate-phase temporaries aliased over the (not-yet-written) W1T/W2T region
    char* G = ws + 10682368;
    unsigned short* hs_hi = (unsigned short*)(G);
    unsigned short* hs_lo = (unsigned short*)(G + 4194304);
    unsigned short* WmT_h = (unsigned short*)(G + 8388608);
    unsigned short* WmT_l = (unsigned short*)(G + 8912896);
    unsigned short* WcT_h = (unsigned short*)(G + 9437184);
    unsigned short* WcT_l = (unsigned short*)(G + 9830400);
    unsigned short* xg_h  = (unsigned short*)(G + 10223616);
    unsigned short* xg_l  = (unsigned short*)(G + 11272192);
    float*          yb    = (float*)(G + 12320768);
    unsigned short* n_h   = (unsigned short*)(G + 14417920);
    unsigned short* n_l   = (unsigned short*)(G + 23855104);
    float*          Zb    = (float*)(G + 33292288);             // ends ~62.8 MB into ws

    k_init<<<1, 64, 0, stream>>>(count, lamb, theta, out, cnt);
    k_split<<<1024, 256, 0, stream>>>(hs, hs_hi, hs_lo);
    k_tsplit<<<dim3(DGc / 32, Dm / 32, 1), 256, 0, stream>>>(Wmlp, WmT_h, WmT_l, Dm, DGc);
    k_tsplit<<<dim3(DGc / 32, DGc / 32, 3), 256, 0, stream>>>(convW, WcT_h, WcT_l, DGc, DGc);
    k_expg<<<1, 256, 0, stream>>>(X, Wst, expg);
    k_s1<<<1, 256, 0, stream>>>(expg, convW, Ahat, S1);
    // xg = silu(hs @ Wmlp) -> hi/lo
    gemm4s<64, Dm, 1><<<dim3(TT / 64, 2), 256, 0, stream>>>(
        hs_hi, hs_lo, WmT_h, WmT_l, nullptr, xg_h, xg_l);
    // y = xg @ convW[0]
    gemm4s<64, DGc, 0><<<dim3(TT / 64, 2), 256, 0, stream>>>(
        xg_h, xg_l, WcT_h, WcT_l, yb, nullptr, nullptr);
    k_l1<<<TT, 256, 0, stream>>>(yb, S1, Ahat, n_h, n_l);
    // layer 2
    gemm4s<128, DGc, 0><<<dim3(TT * Nc / 128, 2), 256, 0, stream>>>(
        n_h, n_l, WcT_h + 65536, WcT_l + 65536, Zb, nullptr, nullptr);
    k_mix2<<<TT, 256, 0, stream>>>(Zb, Ahat, n_h, n_l);
    // layer 3
    gemm4s<128, DGc, 0><<<dim3(TT * Nc / 128, 2), 256, 0, stream>>>(
        n_h, n_l, WcT_h + 131072, WcT_l + 131072, Zb, nullptr, nullptr);
    k_mix3<<<TT / 4, 256, 0, stream>>>(Zb, Ahat, wproj, out, cnt, toklist, wlist);
    // gate temporaries dead; now build FFN weights over that region
    k_tcast<<<dim3(Hc / 32, Dm / 32, Ec), 256, 0, stream>>>(W1, W1T, Dm, Hc);
    k_tcast<<<dim3(Dm / 32, Hc / 32, Ec), 256, 0, stream>>>(W2, W2T, Hc, Dm);
    k_offs<<<1, 1, 0, stream>>>(cnt, poffs, tile_e, tile_m0);
    k_gather<<<PADMAX / 2, 256, 0, stream>>>(hs, cnt, poffs, toklist, wlist,
                                             xb, tokslot, wslot);
    hipMemsetAsync(d_out, 0, (size_t)TT * Dm * sizeof(float), stream);
    k_mfma<Dm, Hc, 0><<<dim3(NTILE_MAX, Hc / 128), 256, 0, stream>>>(
        xb, W1T, tile_e, tile_m0, tokslot, wslot, hb);
    k_mfma<Hc, Dm, 1><<<dim3(NTILE_MAX, Dm / 128), 256, 0, stream>>>(
        hb, W2T, tile_e, tile_m0, tokslot, wslot, out);
}

// Round 4
// 328.731 us; speedup vs baseline: 4.6386x; 1.2244x over previous
//
#include <hip/hip_runtime.h>
#include <math.h>

#define TT 2048   // tokens
#define Dm 1024   // model dim
#define DGc 256   // gate dim
#define Ec 8      // experts
#define Nc 9      // graph nodes
#define Hc 2048   // FFN hidden
#define PADMAX 5120
#define NTILE_MAX 40

typedef __attribute__((ext_vector_type(8))) short short8v;
typedef __attribute__((ext_vector_type(4))) float f32x4;

typedef __attribute__((address_space(1))) const void gvoid;
typedef __attribute__((address_space(3))) void svoid;

__device__ __forceinline__ void gll16(const void* g, void* l) {
    __builtin_amdgcn_global_load_lds((gvoid*)g, (svoid*)l, 16, 0, 0);
}

__device__ __forceinline__ float silu_f(float x) { return x / (1.f + __expf(-x)); }

__device__ __forceinline__ unsigned short bf16_rne(float f) {
    union { float f; unsigned u; } u; u.f = f;
    return (unsigned short)((u.u + 0x7fffu + ((u.u >> 16) & 1u)) >> 16);
}
__device__ __forceinline__ float bf16_to_f(unsigned short h) {
    union { unsigned u; float f; } u; u.u = ((unsigned)h) << 16; return u.f;
}
__device__ __forceinline__ void split2(float x, unsigned short& h, unsigned short& l) {
    h = bf16_rne(x);
    l = bf16_rne(x - bf16_to_f(h));
}

// ---- init: loss tail rows (count / lamb / theta) + zero expert counters ----
__global__ void k_init(const float* count, const float* lamb, const float* theta,
                       float* out, int* cnt) {
    int i = threadIdx.x;
    float* loss = out + (size_t)TT * Dm;
    if (i < Ec)            loss[(size_t)TT * Ec + i]            = count[i];
    else if (i < 2 * Ec)   loss[(size_t)(TT + 1) * Ec + (i - Ec)]   = lamb[0];
    else if (i < 3 * Ec)   loss[(size_t)(TT + 2) * Ec + (i - 2*Ec)] = theta[0];
    if (i < Ec) cnt[i] = 0;
}

// ---- split hs fp32 -> hi/lo bf16 (row-major, K-contig) ----
__global__ __launch_bounds__(256) void k_split(const float* src,
        unsigned short* dh, unsigned short* dl) {
    size_t i = ((size_t)blockIdx.x * 256 + threadIdx.x) * 8;
    float4 v0 = *(const float4*)&src[i];
    float4 v1 = *(const float4*)&src[i + 4];
    ushort4 h0, l0, h1, l1;
    split2(v0.x, h0.x, l0.x); split2(v0.y, h0.y, l0.y);
    split2(v0.z, h0.z, l0.z); split2(v0.w, h0.w, l0.w);
    split2(v1.x, h1.x, l1.x); split2(v1.y, h1.y, l1.y);
    split2(v1.z, h1.z, l1.z); split2(v1.w, h1.w, l1.w);
    *(ushort4*)&dh[i] = h0; *(ushort4*)&dh[i + 4] = h1;
    *(ushort4*)&dl[i] = l0; *(ushort4*)&dl[i + 4] = l1;
}

// ---- transpose+split: src[e][R][C] f32 -> dh/dl [e][C][R] bf16 ----
__global__ __launch_bounds__(256) void k_tsplit(const float* src,
        unsigned short* dh, unsigned short* dl, int R, int C) {
    int e = blockIdx.z;
    int c0 = blockIdx.x * 32, r0 = blockIdx.y * 32;
    const float* S = src + (size_t)e * R * C;
    __shared__ float t[32][36];
    int tid = threadIdx.x;
    int i = tid >> 3, j4 = (tid & 7) * 4;
    *(float4*)&t[i][j4] = *(const float4*)&S[(size_t)(r0 + i) * C + c0 + j4];
    __syncthreads();
    int ci = tid >> 3, r4 = (tid & 7) * 4;
    ushort4 h, l;
    split2(t[r4 + 0][ci], h.x, l.x);
    split2(t[r4 + 1][ci], h.y, l.y);
    split2(t[r4 + 2][ci], h.z, l.z);
    split2(t[r4 + 3][ci], h.w, l.w);
    size_t o = (size_t)e * R * C + (size_t)(c0 + ci) * R + r0 + r4;
    *(ushort4*)&dh[o] = h;
    *(ushort4*)&dl[o] = l;
}

// ---- transpose + cast (hi only, FFN weights) ----
__global__ __launch_bounds__(256) void k_tcast(const float* src, unsigned short* dst,
                                               int R, int C) {
    int e = blockIdx.z;
    int c0 = blockIdx.x * 32, r0 = blockIdx.y * 32;
    const float* S = src + (size_t)e * R * C;
    unsigned short* Dq = dst + (size_t)e * R * C;
    __shared__ float t[32][36];
    int tid = threadIdx.x;
    int i = tid >> 3, j4 = (tid & 7) * 4;
    *(float4*)&t[i][j4] = *(const float4*)&S[(size_t)(r0 + i) * C + c0 + j4];
    __syncthreads();
    int ci = tid >> 3, r4 = (tid & 7) * 4;
    ushort4 v;
    v.x = bf16_rne(t[r4 + 0][ci]);
    v.y = bf16_rne(t[r4 + 1][ci]);
    v.z = bf16_rne(t[r4 + 2][ci]);
    v.w = bf16_rne(t[r4 + 3][ci]);
    *(ushort4*)&Dq[(size_t)(c0 + ci) * R + r0 + r4] = v;
}

// ---- expg accumulate (split-K): expg_raw[e][g] += X[e][kb:kb+64] . Wst ----
__global__ __launch_bounds__(256) void k_expgA(const float* X, const float* Wst,
                                               float* expg_raw) {
    int g = threadIdx.x;
    int kb = blockIdx.x * 64;
    __shared__ float xs[Ec][64];
    if (g < 128) {
        int e = g >> 4;
        int k4 = (g & 15) * 4;
        *(float4*)&xs[e][k4] = *(const float4*)&X[(size_t)e * Dm + kb + k4];
    }
    __syncthreads();
    float acc[Ec];
#pragma unroll
    for (int e = 0; e < Ec; e++) acc[e] = 0.f;
#pragma unroll 4
    for (int k = 0; k < 64; k++) {
        float w = Wst[(size_t)(kb + k) * DGc + g];
#pragma unroll
        for (int e = 0; e < Ec; e++) acc[e] += xs[e][k] * w;
    }
#pragma unroll
    for (int e = 0; e < Ec; e++) atomicAdd(&expg_raw[e * DGc + g], acc[e]);
}

// ---- silu in place over expg ----
__global__ void k_expgB(float* expg) {
    int i = blockIdx.x * 256 + threadIdx.x;
    expg[i] = silu_f(expg[i]);
}

// ---- G[m][g] += expg[m][kb:kb+32] . W0 (split-K) ----
__global__ __launch_bounds__(256) void k_gA(const float* expg, const float* W0,
                                            float* G) {
    int g = threadIdx.x;
    int kb = blockIdx.x * 32;
    __shared__ float xs[Ec][32];
    xs[g >> 5][g & 31] = expg[(size_t)(g >> 5) * DGc + kb + (g & 31)];
    __syncthreads();
    float acc[Ec];
#pragma unroll
    for (int e = 0; e < Ec; e++) acc[e] = 0.f;
#pragma unroll 4
    for (int k = 0; k < 32; k++) {
        float w = W0[(size_t)(kb + k) * DGc + g];
#pragma unroll
        for (int e = 0; e < Ec; e++) acc[e] += xs[e][k] * w;
    }
#pragma unroll
    for (int e = 0; e < Ec; e++) atomicAdd(&G[e * DGc + g], acc[e]);
}

// ---- S1[n] = sum_{m<8} A[n,m] * G[m]  (trivial) ----
__global__ __launch_bounds__(256) void k_s1fin(const float* G, const float* Ahat,
                                               float* S1) {
    int g = threadIdx.x;
    float Gl[Ec];
#pragma unroll
    for (int m = 0; m < Ec; m++) Gl[m] = G[m * DGc + g];
#pragma unroll
    for (int n = 0; n < Nc; n++) {
        float s = 0.f;
#pragma unroll
        for (int m = 0; m < Ec; m++) s += Ahat[n * Nc + m] * Gl[m];
        S1[n * DGc + g] = s;
    }
}

// ---- split-bf16 4-pass MFMA GEMM: C[M,256] = A[M,K] @ B^T (B:[256,K]) ----
template<int BM, int KD, int EPI>
__global__ __launch_bounds__(256) void gemm4s(const unsigned short* Ah,
        const unsigned short* Al, const unsigned short* Bh, const unsigned short* Bl,
        float* Cf, unsigned short* Oh, unsigned short* Ol) {
    constexpr int FM = BM / 32;
    constexpr int AR = BM / 64;
    int m0 = blockIdx.x * BM, n0 = blockIdx.y * 128;
    __shared__ __align__(16) unsigned short AsH[BM * 32];
    __shared__ __align__(16) unsigned short AsL[BM * 32];
    __shared__ __align__(16) unsigned short BsH[128 * 32];
    __shared__ __align__(16) unsigned short BsL[128 * 32];
    int tid = threadIdx.x, lane = tid & 63, wid = tid >> 6;
    int wr = wid >> 1, wc = wid & 1, lo = lane & 15, hi = lane >> 4;

    f32x4 acc[FM][4];
#pragma unroll
    for (int m = 0; m < FM; m++)
#pragma unroll
        for (int n = 0; n < 4; n++) acc[m][n] = (f32x4)(0.f);

    size_t aoff = (size_t)(m0 + (tid >> 2)) * KD + (tid & 3) * 8;
    size_t boff = (size_t)(n0 + (tid >> 2)) * KD + (tid & 3) * 8;

    for (int kb = 0; kb < KD; kb += 32) {
#pragma unroll
        for (int r = 0; r < AR; r++) {
            gll16(Ah + aoff + (size_t)r * 64 * KD + kb, (char*)AsH + r * 4096 + tid * 16);
            gll16(Al + aoff + (size_t)r * 64 * KD + kb, (char*)AsL + r * 4096 + tid * 16);
        }
#pragma unroll
        for (int r = 0; r < 2; r++) {
            gll16(Bh + boff + (size_t)r * 64 * KD + kb, (char*)BsH + r * 4096 + tid * 16);
            gll16(Bl + boff + (size_t)r * 64 * KD + kb, (char*)BsL + r * 4096 + tid * 16);
        }
        __syncthreads();
        short8v ah[FM], al[FM], bh[4], bl[4];
#pragma unroll
        for (int m = 0; m < FM; m++) {
            ah[m] = *(const short8v*)&AsH[(wr * (BM / 2) + m * 16 + lo) * 32 + hi * 8];
            al[m] = *(const short8v*)&AsL[(wr * (BM / 2) + m * 16 + lo) * 32 + hi * 8];
        }
#pragma unroll
        for (int n = 0; n < 4; n++) {
            bh[n] = *(const short8v*)&BsH[(wc * 64 + n * 16 + lo) * 32 + hi * 8];
            bl[n] = *(const short8v*)&BsL[(wc * 64 + n * 16 + lo) * 32 + hi * 8];
        }
#pragma unroll
        for (int m = 0; m < FM; m++)
#pragma unroll
            for (int n = 0; n < 4; n++)
                acc[m][n] = __builtin_amdgcn_mfma_f32_16x16x32_bf16(ah[m], bh[n], acc[m][n], 0, 0, 0);
#pragma unroll
        for (int m = 0; m < FM; m++)
#pragma unroll
            for (int n = 0; n < 4; n++)
                acc[m][n] = __builtin_amdgcn_mfma_f32_16x16x32_bf16(ah[m], bl[n], acc[m][n], 0, 0, 0);
#pragma unroll
        for (int m = 0; m < FM; m++)
#pragma unroll
            for (int n = 0; n < 4; n++)
                acc[m][n] = __builtin_amdgcn_mfma_f32_16x16x32_bf16(al[m], bh[n], acc[m][n], 0, 0, 0);
#pragma unroll
        for (int m = 0; m < FM; m++)
#pragma unroll
            for (int n = 0; n < 4; n++)
                acc[m][n] = __builtin_amdgcn_mfma_f32_16x16x32_bf16(al[m], bl[n], acc[m][n], 0, 0, 0);
        __syncthreads();
    }

#pragma unroll
    for (int m = 0; m < FM; m++) {
#pragma unroll
        for (int n = 0; n < 4; n++) {
            int col = n0 + wc * 64 + n * 16 + lo;
#pragma unroll
            for (int r = 0; r < 4; r++) {
                int row = m0 + wr * (BM / 2) + m * 16 + hi * 4 + r;
                if (EPI == 0) {
                    Cf[(size_t)row * 256 + col] = acc[m][n][r];
                } else {
                    float s = silu_f(acc[m][n][r]);
                    unsigned short h, l;
                    split2(s, h, l);
                    Oh[(size_t)row * 256 + col] = h;
                    Ol[(size_t)row * 256 + col] = l;
                }
            }
        }
    }
}

// ---- layer-1 build: node1[t,n] = silu(S1[n] + A[n,8]*y[t]) -> hi/lo ----
__global__ __launch_bounds__(256) void k_l1(const float* y, const float* S1,
        const float* Ahat, unsigned short* nh, unsigned short* nl) {
    int t = blockIdx.x, g = threadIdx.x;
    float yv = y[(size_t)t * DGc + g];
#pragma unroll
    for (int n = 0; n < Nc; n++) {
        float c = Ahat[n * Nc + Ec];
        float s = silu_f(S1[n * DGc + g] + c * yv);
        unsigned short h, l;
        split2(s, h, l);
        size_t o = ((size_t)t * Nc + n) * DGc + g;
        nh[o] = h; nl[o] = l;
    }
}

// ---- mix: node[t,n] = silu(sum_m A[n,m] Z[t,m]) -> hi/lo ----
__global__ __launch_bounds__(256) void k_mix2(const float* Z, const float* Ahat,
        unsigned short* nh, unsigned short* nl) {
    int t = blockIdx.x, g = threadIdx.x;
    __shared__ float A[Nc * Nc];
    if (g < Nc * Nc) A[g] = Ahat[g];
    __syncthreads();
    float z[Nc];
#pragma unroll
    for (int m = 0; m < Nc; m++) z[m] = Z[((size_t)t * Nc + m) * DGc + g];
#pragma unroll
    for (int n = 0; n < Nc; n++) {
        float s = 0.f;
#pragma unroll
        for (int m = 0; m < Nc; m++) s += A[n * Nc + m] * z[m];
        s = silu_f(s);
        unsigned short h, l;
        split2(s, h, l);
        size_t o = ((size_t)t * Nc + n) * DGc + g;
        nh[o] = h; nl[o] = l;
    }
}

// ---- final mix + logits + softmax + top2 + routing (1 wave per token) ----
__global__ __launch_bounds__(256) void k_mix3(const float* Z, const float* Ahat,
        const float* wproj, float* out, int* cnt, int* toklist, float* wlist) {
    __shared__ float A[Nc * Nc];
    __shared__ float wp[DGc];
    int tid = threadIdx.x;
    if (tid < Nc * Nc) A[tid] = Ahat[tid];
    wp[tid] = wproj[tid];
    __syncthreads();
    int wid = tid >> 6, lane = tid & 63;
    int t = blockIdx.x * 4 + wid;
    float lg[Ec];
#pragma unroll
    for (int e = 0; e < Ec; e++) lg[e] = 0.f;
#pragma unroll
    for (int j = 0; j < 4; j++) {
        int g = j * 64 + lane;
        float z[Nc];
#pragma unroll
        for (int m = 0; m < Nc; m++) z[m] = Z[((size_t)t * Nc + m) * DGc + g];
#pragma unroll
        for (int e = 0; e < Ec; e++) {
            float s = 0.f;
#pragma unroll
            for (int m = 0; m < Nc; m++) s += A[e * Nc + m] * z[m];
            lg[e] += silu_f(s) * wp[g];
        }
    }
#pragma unroll
    for (int off = 32; off >= 1; off >>= 1) {
#pragma unroll
        for (int e = 0; e < Ec; e++) lg[e] += __shfl_xor(lg[e], off);
    }
    if (lane == 0) {
        float mx = -1e30f;
#pragma unroll
        for (int e = 0; e < Ec; e++) mx = fmaxf(mx, lg[e]);
        float pr[Ec], s = 0.f;
#pragma unroll
        for (int e = 0; e < Ec; e++) { pr[e] = __expf(lg[e] - mx); s += pr[e]; }
        float inv = 1.f / s;
        float* lrow = out + (size_t)TT * Dm + (size_t)t * Ec;
#pragma unroll
        for (int e = 0; e < Ec; e++) { pr[e] *= inv; lrow[e] = pr[e]; }
        int i0 = 0; float v0 = pr[0];
#pragma unroll
        for (int e = 1; e < Ec; e++) if (pr[e] > v0) { v0 = pr[e]; i0 = e; }
        int i1 = -1; float v1 = -1e30f;
#pragma unroll
        for (int e = 0; e < Ec; e++) if (e != i0 && pr[e] > v1) { v1 = pr[e]; i1 = e; }
        float* rowT = out + (size_t)TT * Dm + (size_t)TT * Ec;
        atomicAdd(&rowT[i0], 2.f * v0);
        atomicAdd(&rowT[i1], 2.f * v1);
        float winv = 1.f / (v0 + v1);
        int p0 = atomicAdd(&cnt[i0], 1);
        toklist[i0 * TT + p0] = t; wlist[i0 * TT + p0] = v0 * winv;
        int p1 = atomicAdd(&cnt[i1], 1);
        toklist[i1 * TT + p1] = t; wlist[i1 * TT + p1] = v1 * winv;
    }
}

// ---- padded offsets + tile map ----
__global__ void k_offs(const int* cnt, int* poffs, int* tile_e, int* tile_m0) {
    if (threadIdx.x == 0) {
        int pad = 0, nt = 0;
        for (int e = 0; e < Ec; e++) {
            poffs[e] = pad;
            int te = (cnt[e] + 127) >> 7;
            for (int i = 0; i < te; i++) { tile_e[nt] = e; tile_m0[nt] = pad + i * 128; nt++; }
            pad += te * 128;
        }
        poffs[Ec] = pad;
        for (; nt < NTILE_MAX; nt++) { tile_e[nt] = -1; tile_m0[nt] = 0; }
    }
}

// ---- gather routed tokens into padded slot-major bf16 buffer + slot maps ----
__global__ __launch_bounds__(256) void k_gather(const float* hs, const int* cnt,
        const int* poffs, const int* toklist, const float* wlist,
        unsigned short* xb, int* tokslot, float* wslot) {
    int tid = threadIdx.x;
    int s = blockIdx.x * 2 + (tid >> 7);
    int j = (tid & 127) * 8;
    int e = 0;
#pragma unroll
    for (int q = 1; q < Ec; q++) if (s >= poffs[q]) e = q;
    int pos = s - poffs[e];
    int tok = -1; float w = 0.f;
    if (pos < cnt[e]) { tok = toklist[e * TT + pos]; w = wlist[e * TT + pos]; }
    if (j == 0) { tokslot[s] = tok; wslot[s] = w; }
    ushort4 o0, o1;
    if (tok >= 0) {
        const float* xr = hs + (size_t)tok * Dm + j;
        o0.x = bf16_rne(xr[0]); o0.y = bf16_rne(xr[1]); o0.z = bf16_rne(xr[2]); o0.w = bf16_rne(xr[3]);
        o1.x = bf16_rne(xr[4]); o1.y = bf16_rne(xr[5]); o1.z = bf16_rne(xr[6]); o1.w = bf16_rne(xr[7]);
    } else {
        o0 = make_ushort4(0, 0, 0, 0); o1 = o0;
    }
    *(ushort4*)&xb[(size_t)s * Dm + j] = o0;
    *(ushort4*)&xb[(size_t)s * Dm + j + 4] = o1;
}

// ---- FFN MFMA grouped GEMM ----
template<int KDIM, int NDIM, int MODE>
__global__ __launch_bounds__(256) void k_mfma(const unsigned short* Abuf,
        const unsigned short* Wt, const int* tile_e, const int* tile_m0,
        const int* tokslot, const float* wslot, void* outp) {
    int e = tile_e[blockIdx.x];
    if (e < 0) return;
    int m0 = tile_m0[blockIdx.x];
    int n0 = blockIdx.y * 128;
    const unsigned short* Bg = Wt + (size_t)e * NDIM * KDIM;
    __shared__ __align__(16) unsigned short As[128 * 32];
    __shared__ __align__(16) unsigned short Bs[128 * 32];
    int tid = threadIdx.x;
    int lane = tid & 63;
    int wid = tid >> 6;
    int wr = wid >> 1, wc = wid & 1;
    int lo = lane & 15, hi = lane >> 4;

    f32x4 acc[4][4];
#pragma unroll
    for (int m = 0; m < 4; m++)
#pragma unroll
        for (int n = 0; n < 4; n++) acc[m][n] = (f32x4)(0.f);

    int arow = tid >> 2;
    int acol = (tid & 3) * 8;
    const unsigned short* Ag = Abuf + (size_t)m0 * KDIM;
    const unsigned short* Bt = Bg + (size_t)n0 * KDIM;

    for (int kb = 0; kb < KDIM; kb += 32) {
        gll16(Ag + (size_t)arow * KDIM + kb + acol,        (char*)As + tid * 16);
        gll16(Ag + (size_t)(arow + 64) * KDIM + kb + acol, (char*)As + 4096 + tid * 16);
        gll16(Bt + (size_t)arow * KDIM + kb + acol,        (char*)Bs + tid * 16);
        gll16(Bt + (size_t)(arow + 64) * KDIM + kb + acol, (char*)Bs + 4096 + tid * 16);
        __syncthreads();
        short8v a[4], b[4];
#pragma unroll
        for (int m = 0; m < 4; m++)
            a[m] = *(const short8v*)&As[(wr * 64 + m * 16 + lo) * 32 + hi * 8];
#pragma unroll
        for (int n = 0; n < 4; n++)
            b[n] = *(const short8v*)&Bs[(wc * 64 + n * 16 + lo) * 32 + hi * 8];
#pragma unroll
        for (int m = 0; m < 4; m++)
#pragma unroll
            for (int n = 0; n < 4; n++)
                acc[m][n] = __builtin_amdgcn_mfma_f32_16x16x32_bf16(a[m], b[n], acc[m][n], 0, 0, 0);
        __syncthreads();
    }

    if (MODE == 0) {
        unsigned short* O = (unsigned short*)outp;
#pragma unroll
        for (int m = 0; m < 4; m++) {
#pragma unroll
            for (int n = 0; n < 4; n++) {
                int col = n0 + wc * 64 + n * 16 + lo;
#pragma unroll
                for (int r = 0; r < 4; r++) {
                    int row = m0 + wr * 64 + m * 16 + hi * 4 + r;
                    O[(size_t)row * NDIM + col] = bf16_rne(silu_f(acc[m][n][r]));
                }
            }
        }
    } else {
        float* O = (float*)outp;
#pragma unroll
        for (int m = 0; m < 4; m++) {
            int toks[4]; float ws[4];
#pragma unroll
            for (int r = 0; r < 4; r++) {
                int row = m0 + wr * 64 + m * 16 + hi * 4 + r;
                toks[r] = tokslot[row];
                ws[r] = wslot[row];
            }
#pragma unroll
            for (int n = 0; n < 4; n++) {
                int col = n0 + wc * 64 + n * 16 + lo;
#pragma unroll
                for (int r = 0; r < 4; r++) {
                    if (toks[r] >= 0)
                        atomicAdd(&O[(size_t)toks[r] * Dm + col], ws[r] * acc[m][n][r]);
                }
            }
        }
    }
}

extern "C" void kernel_launch(void* const* d_in, const int* in_sizes, int n_in,
                              void* d_out, int out_size, void* d_ws, size_t ws_size,
                              hipStream_t stream) {
    const float* hs    = (const float*)d_in[0];
    const float* X     = (const float*)d_in[1];
    const float* Wmlp  = (const float*)d_in[2];
    const float* Wst   = (const float*)d_in[3];
    const float* convW = (const float*)d_in[4];
    const float* wproj = (const float*)d_in[5];
    const float* W1    = (const float*)d_in[6];
    const float* W2    = (const float*)d_in[7];
    const float* lamb  = (const float*)d_in[8];
    const float* theta = (const float*)d_in[9];
    const float* count = (const float*)d_in[10];
    const float* Ahat  = (const float*)d_in[11];
    float* out = (float*)d_out;
    char* ws = (char*)d_ws;

    // persistent layout
    float*          expg    = (float*)ws;                       // 8 KB (raw then silu'd)
    int*            cnt     = (int*)(ws + 8192);
    int*            poffs   = (int*)(ws + 8320);
    int*            tile_e  = (int*)(ws + 8448);
    int*            tile_m0 = (int*)(ws + 8704);
    float*          S1      = (float*)(ws + 9216);
    int*            toklist = (int*)(ws + 20480);
    float*          wlist   = (float*)(ws + 86016);
    int*            tokslot = (int*)(ws + 151552);
    float*          wslot   = (float*)(ws + 172032);
    unsigned short* xb      = (unsigned short*)(ws + 196608);   // 10.5 MB
    unsigned short* W1T     = (unsigned short*)(ws + 10682368); // 33.5 MB
    unsigned short* W2T     = (unsigned short*)(ws + 44236800); // 33.5 MB
    unsigned short* hb      = (unsigned short*)(ws + 77791232); // 21 MB

    // gate-phase temporaries aliased over the (not-yet-written) W1T/W2T region
    char* G = ws + 10682368;
    unsigned short* hs_hi = (unsigned short*)(G);
    unsigned short* hs_lo = (unsigned short*)(G + 4194304);
    unsigned short* WmT_h = (unsigned short*)(G + 8388608);
    unsigned short* WmT_l = (unsigned short*)(G + 8912896);
    unsigned short* WcT_h = (unsigned short*)(G + 9437184);
    unsigned short* WcT_l = (unsigned short*)(G + 9830400);
    unsigned short* xg_h  = (unsigned short*)(G + 10223616);
    unsigned short* xg_l  = (unsigned short*)(G + 11272192);
    float*          yb    = (float*)(G + 12320768);
    unsigned short* n_h   = (unsigned short*)(G + 14417920);
    unsigned short* n_l   = (unsigned short*)(G + 23855104);
    float*          Zb    = (float*)(G + 33292288);             // 18.9 MB -> ends G+52.2MB
    float*          Gbuf  = (float*)(G + 52166656);             // 8 KB

    k_init<<<1, 64, 0, stream>>>(count, lamb, theta, out, cnt);
    hipMemsetAsync(expg, 0, Ec * DGc * sizeof(float), stream);
    hipMemsetAsync(Gbuf, 0, Ec * DGc * sizeof(float), stream);
    k_split<<<1024, 256, 0, stream>>>(hs, hs_hi, hs_lo);
    k_tsplit<<<dim3(DGc / 32, Dm / 32, 1), 256, 0, stream>>>(Wmlp, WmT_h, WmT_l, Dm, DGc);
    k_tsplit<<<dim3(DGc / 32, DGc / 32, 3), 256, 0, stream>>>(convW, WcT_h, WcT_l, DGc, DGc);
    k_expgA<<<Dm / 64, 256, 0, stream>>>(X, Wst, expg);
    k_expgB<<<Ec, 256, 0, stream>>>(expg);
    k_gA<<<DGc / 32, 256, 0, stream>>>(expg, convW, Gbuf);
    k_s1fin<<<1, 256, 0, stream>>>(Gbuf, Ahat, S1);
    // xg = silu(hs @ Wmlp) -> hi/lo
    gemm4s<64, Dm, 1><<<dim3(TT / 64, 2), 256, 0, stream>>>(
        hs_hi, hs_lo, WmT_h, WmT_l, nullptr, xg_h, xg_l);
    // y = xg @ convW[0]
    gemm4s<64, DGc, 0><<<dim3(TT / 64, 2), 256, 0, stream>>>(
        xg_h, xg_l, WcT_h, WcT_l, yb, nullptr, nullptr);
    k_l1<<<TT, 256, 0, stream>>>(yb, S1, Ahat, n_h, n_l);
    // layer 2
    gemm4s<128, DGc, 0><<<dim3(TT * Nc / 128, 2), 256, 0, stream>>>(
        n_h, n_l, WcT_h + 65536, WcT_l + 65536, Zb, nullptr, nullptr);
    k_mix2<<<TT, 256, 0, stream>>>(Zb, Ahat, n_h, n_l);
    // layer 3
    gemm4s<128, DGc, 0><<<dim3(TT * Nc / 128, 2), 256, 0, stream>>>(
        n_h, n_l, WcT_h + 131072, WcT_l + 131072, Zb, nullptr, nullptr);
    k_mix3<<<TT / 4, 256, 0, stream>>>(Zb, Ahat, wproj, out, cnt, toklist, wlist);
    // gate temporaries dead; now build FFN weights over that region
    k_tcast<<<dim3(Hc / 32, Dm / 32, Ec), 256, 0, stream>>>(W1, W1T, Dm, Hc);
    k_tcast<<<dim3(Dm / 32, Hc / 32, Ec), 256, 0, stream>>>(W2, W2T, Hc, Dm);
    k_offs<<<1, 1, 0, stream>>>(cnt, poffs, tile_e, tile_m0);
    k_gather<<<PADMAX / 2, 256, 0, stream>>>(hs, cnt, poffs, toklist, wlist,
                                             xb, tokslot, wslot);
    hipMemsetAsync(d_out, 0, (size_t)TT * Dm * sizeof(float), stream);
    k_mfma<Dm, Hc, 0><<<dim3(NTILE_MAX, Hc / 128), 256, 0, stream>>>(
        xb, W1T, tile_e, tile_m0, tokslot, wslot, hb);
    k_mfma<Hc, Dm, 1><<<dim3(NTILE_MAX, Dm / 128), 256, 0, stream>>>(
        hb, W2T, tile_e, tile_m0, tokslot, wslot, out);
}

// Round 5
// 314.683 us; speedup vs baseline: 4.8457x; 1.0446x over previous
//
#include <hip/hip_runtime.h>
#include <math.h>

#define TT 2048   // tokens
#define Dm 1024   // model dim
#define DGc 256   // gate dim
#define Ec 8      // experts
#define Nc 9      // graph nodes
#define Hc 2048   // FFN hidden
#define PADMAX 5120
#define NTILE_MAX 40

typedef __attribute__((ext_vector_type(8))) short short8v;
typedef __attribute__((ext_vector_type(4))) float f32x4;

typedef __attribute__((address_space(1))) const void gvoid;
typedef __attribute__((address_space(3))) void svoid;

__device__ __forceinline__ void gll16(const void* g, void* l) {
    __builtin_amdgcn_global_load_lds((gvoid*)g, (svoid*)l, 16, 0, 0);
}

__device__ __forceinline__ float silu_f(float x) { return x / (1.f + __expf(-x)); }

__device__ __forceinline__ unsigned short bf16_rne(float f) {
    union { float f; unsigned u; } u; u.f = f;
    return (unsigned short)((u.u + 0x7fffu + ((u.u >> 16) & 1u)) >> 16);
}
__device__ __forceinline__ float bf16_to_f(unsigned short h) {
    union { unsigned u; float f; } u; u.u = ((unsigned)h) << 16; return u.f;
}
__device__ __forceinline__ void split2(float x, unsigned short& h, unsigned short& l) {
    h = bf16_rne(x);
    l = bf16_rne(x - bf16_to_f(h));
}

// ---- init: loss tail rows (count / lamb / theta) + zero expert counters ----
__global__ void k_init(const float* count, const float* lamb, const float* theta,
                       float* out, int* cnt) {
    int i = threadIdx.x;
    float* loss = out + (size_t)TT * Dm;
    if (i < Ec)            loss[(size_t)TT * Ec + i]            = count[i];
    else if (i < 2 * Ec)   loss[(size_t)(TT + 1) * Ec + (i - Ec)]   = lamb[0];
    else if (i < 3 * Ec)   loss[(size_t)(TT + 2) * Ec + (i - 2*Ec)] = theta[0];
    if (i < Ec) cnt[i] = 0;
}

// ---- split hs fp32 -> hi/lo bf16 (row-major, K-contig) ----
__global__ __launch_bounds__(256) void k_split(const float* src,
        unsigned short* dh, unsigned short* dl) {
    size_t i = ((size_t)blockIdx.x * 256 + threadIdx.x) * 8;
    float4 v0 = *(const float4*)&src[i];
    float4 v1 = *(const float4*)&src[i + 4];
    ushort4 h0, l0, h1, l1;
    split2(v0.x, h0.x, l0.x); split2(v0.y, h0.y, l0.y);
    split2(v0.z, h0.z, l0.z); split2(v0.w, h0.w, l0.w);
    split2(v1.x, h1.x, l1.x); split2(v1.y, h1.y, l1.y);
    split2(v1.z, h1.z, l1.z); split2(v1.w, h1.w, l1.w);
    *(ushort4*)&dh[i] = h0; *(ushort4*)&dh[i + 4] = h1;
    *(ushort4*)&dl[i] = l0; *(ushort4*)&dl[i + 4] = l1;
}

// ---- transpose+split: src[e][R][C] f32 -> dh/dl [e][C][R] bf16 ----
__global__ __launch_bounds__(256) void k_tsplit(const float* src,
        unsigned short* dh, unsigned short* dl, int R, int C) {
    int e = blockIdx.z;
    int c0 = blockIdx.x * 32, r0 = blockIdx.y * 32;
    const float* S = src + (size_t)e * R * C;
    __shared__ float t[32][36];
    int tid = threadIdx.x;
    int i = tid >> 3, j4 = (tid & 7) * 4;
    *(float4*)&t[i][j4] = *(const float4*)&S[(size_t)(r0 + i) * C + c0 + j4];
    __syncthreads();
    int ci = tid >> 3, r4 = (tid & 7) * 4;
    ushort4 h, l;
    split2(t[r4 + 0][ci], h.x, l.x);
    split2(t[r4 + 1][ci], h.y, l.y);
    split2(t[r4 + 2][ci], h.z, l.z);
    split2(t[r4 + 3][ci], h.w, l.w);
    size_t o = (size_t)e * R * C + (size_t)(c0 + ci) * R + r0 + r4;
    *(ushort4*)&dh[o] = h;
    *(ushort4*)&dl[o] = l;
}

// ---- transpose + cast (hi only, FFN weights) ----
__global__ __launch_bounds__(256) void k_tcast(const float* src, unsigned short* dst,
                                               int R, int C) {
    int e = blockIdx.z;
    int c0 = blockIdx.x * 32, r0 = blockIdx.y * 32;
    const float* S = src + (size_t)e * R * C;
    unsigned short* Dq = dst + (size_t)e * R * C;
    __shared__ float t[32][36];
    int tid = threadIdx.x;
    int i = tid >> 3, j4 = (tid & 7) * 4;
    *(float4*)&t[i][j4] = *(const float4*)&S[(size_t)(r0 + i) * C + c0 + j4];
    __syncthreads();
    int ci = tid >> 3, r4 = (tid & 7) * 4;
    ushort4 v;
    v.x = bf16_rne(t[r4 + 0][ci]);
    v.y = bf16_rne(t[r4 + 1][ci]);
    v.z = bf16_rne(t[r4 + 2][ci]);
    v.w = bf16_rne(t[r4 + 3][ci]);
    *(ushort4*)&Dq[(size_t)(c0 + ci) * R + r0 + r4] = v;
}

// ---- expg accumulate (split-K): expg_raw[e][g] += X[e][kb:kb+64] . Wst ----
__global__ __launch_bounds__(256) void k_expgA(const float* X, const float* Wst,
                                               float* expg_raw) {
    int g = threadIdx.x;
    int kb = blockIdx.x * 64;
    __shared__ float xs[Ec][64];
    if (g < 128) {
        int e = g >> 4;
        int k4 = (g & 15) * 4;
        *(float4*)&xs[e][k4] = *(const float4*)&X[(size_t)e * Dm + kb + k4];
    }
    __syncthreads();
    float acc[Ec];
#pragma unroll
    for (int e = 0; e < Ec; e++) acc[e] = 0.f;
#pragma unroll 4
    for (int k = 0; k < 64; k++) {
        float w = Wst[(size_t)(kb + k) * DGc + g];
#pragma unroll
        for (int e = 0; e < Ec; e++) acc[e] += xs[e][k] * w;
    }
#pragma unroll
    for (int e = 0; e < Ec; e++) atomicAdd(&expg_raw[e * DGc + g], acc[e]);
}

// ---- G[m][g] += silu(expg_raw[m])[kb:kb+32] . W0 (split-K, silu folded in) ----
__global__ __launch_bounds__(256) void k_gA(const float* expg_raw, const float* W0,
                                            float* G) {
    int g = threadIdx.x;
    int kb = blockIdx.x * 32;
    __shared__ float xs[Ec][32];
    xs[g >> 5][g & 31] = silu_f(expg_raw[(size_t)(g >> 5) * DGc + kb + (g & 31)]);
    __syncthreads();
    float acc[Ec];
#pragma unroll
    for (int e = 0; e < Ec; e++) acc[e] = 0.f;
#pragma unroll 4
    for (int k = 0; k < 32; k++) {
        float w = W0[(size_t)(kb + k) * DGc + g];
#pragma unroll
        for (int e = 0; e < Ec; e++) acc[e] += xs[e][k] * w;
    }
#pragma unroll
    for (int e = 0; e < Ec; e++) atomicAdd(&G[e * DGc + g], acc[e]);
}

// ---- S1[n] = sum_{m<8} A[n,m] * G[m]  (trivial) ----
__global__ __launch_bounds__(256) void k_s1fin(const float* G, const float* Ahat,
                                               float* S1) {
    int g = threadIdx.x;
    float Gl[Ec];
#pragma unroll
    for (int m = 0; m < Ec; m++) Gl[m] = G[m * DGc + g];
#pragma unroll
    for (int n = 0; n < Nc; n++) {
        float s = 0.f;
#pragma unroll
        for (int m = 0; m < Ec; m++) s += Ahat[n * Nc + m] * Gl[m];
        S1[n * DGc + g] = s;
    }
}

// ---- split-bf16 3-pass MFMA GEMM: C[M,256] = A[M,K] @ B^T (B:[256,K]) ----
// hh + hl + lh passes (ll dropped, ~1e-5 relative). Bank-conflict-free via
// source-pre-swizzle (gll16 writes LDS linearly) + XOR'd ds_read address.
template<int BM, int KD, int EPI>
__global__ __launch_bounds__(256) void gemm4s(const unsigned short* Ah,
        const unsigned short* Al, const unsigned short* Bh, const unsigned short* Bl,
        float* Cf, unsigned short* Oh, unsigned short* Ol) {
    constexpr int FM = BM / 32;
    constexpr int AR = BM / 64;
    int m0 = blockIdx.x * BM, n0 = blockIdx.y * 128;
    __shared__ __align__(16) unsigned short AsH[BM * 32];
    __shared__ __align__(16) unsigned short AsL[BM * 32];
    __shared__ __align__(16) unsigned short BsH[128 * 32];
    __shared__ __align__(16) unsigned short BsL[128 * 32];
    int tid = threadIdx.x, lane = tid & 63, wid = tid >> 6;
    int wr = wid >> 1, wc = wid & 1, lo = lane & 15, hi = lane >> 4;

    f32x4 acc[FM][4];
#pragma unroll
    for (int m = 0; m < FM; m++)
#pragma unroll
        for (int n = 0; n < 4; n++) acc[m][n] = (f32x4)(0.f);

    // staging: LDS slot (row=tid>>2, h=tid&3) sources global col-block h^s(row)
    int sW = (tid >> 3) & 3;                       // (row>>1)&3 for row=tid>>2
    size_t aoff = (size_t)(m0 + (tid >> 2)) * KD + ((tid & 3) ^ sW) * 8;
    size_t boff = (size_t)(n0 + (tid >> 2)) * KD + ((tid & 3) ^ sW) * 8;
    // read: XOR hi with s(row) = (lo>>1)&3
    int hixor = (hi ^ ((lo >> 1) & 3)) * 8;

    for (int kb = 0; kb < KD; kb += 32) {
#pragma unroll
        for (int r = 0; r < AR; r++) {
            gll16(Ah + aoff + (size_t)r * 64 * KD + kb, (char*)AsH + r * 4096 + tid * 16);
            gll16(Al + aoff + (size_t)r * 64 * KD + kb, (char*)AsL + r * 4096 + tid * 16);
        }
#pragma unroll
        for (int r = 0; r < 2; r++) {
            gll16(Bh + boff + (size_t)r * 64 * KD + kb, (char*)BsH + r * 4096 + tid * 16);
            gll16(Bl + boff + (size_t)r * 64 * KD + kb, (char*)BsL + r * 4096 + tid * 16);
        }
        __syncthreads();
        short8v ah[FM], al[FM], bh[4], bl[4];
#pragma unroll
        for (int m = 0; m < FM; m++) {
            ah[m] = *(const short8v*)&AsH[(wr * (BM / 2) + m * 16 + lo) * 32 + hixor];
            al[m] = *(const short8v*)&AsL[(wr * (BM / 2) + m * 16 + lo) * 32 + hixor];
        }
#pragma unroll
        for (int n = 0; n < 4; n++) {
            bh[n] = *(const short8v*)&BsH[(wc * 64 + n * 16 + lo) * 32 + hixor];
            bl[n] = *(const short8v*)&BsL[(wc * 64 + n * 16 + lo) * 32 + hixor];
        }
#pragma unroll
        for (int m = 0; m < FM; m++)
#pragma unroll
            for (int n = 0; n < 4; n++)
                acc[m][n] = __builtin_amdgcn_mfma_f32_16x16x32_bf16(ah[m], bh[n], acc[m][n], 0, 0, 0);
#pragma unroll
        for (int m = 0; m < FM; m++)
#pragma unroll
            for (int n = 0; n < 4; n++)
                acc[m][n] = __builtin_amdgcn_mfma_f32_16x16x32_bf16(ah[m], bl[n], acc[m][n], 0, 0, 0);
#pragma unroll
        for (int m = 0; m < FM; m++)
#pragma unroll
            for (int n = 0; n < 4; n++)
                acc[m][n] = __builtin_amdgcn_mfma_f32_16x16x32_bf16(al[m], bh[n], acc[m][n], 0, 0, 0);
        __syncthreads();
    }

#pragma unroll
    for (int m = 0; m < FM; m++) {
#pragma unroll
        for (int n = 0; n < 4; n++) {
            int col = n0 + wc * 64 + n * 16 + lo;
#pragma unroll
            for (int r = 0; r < 4; r++) {
                int row = m0 + wr * (BM / 2) + m * 16 + hi * 4 + r;
                if (EPI == 0) {
                    Cf[(size_t)row * 256 + col] = acc[m][n][r];
                } else {
                    float s = silu_f(acc[m][n][r]);
                    unsigned short h, l;
                    split2(s, h, l);
                    Oh[(size_t)row * 256 + col] = h;
                    Ol[(size_t)row * 256 + col] = l;
                }
            }
        }
    }
}

// ---- layer-1 build: node1[t,n] = silu(S1[n] + A[n,8]*y[t]) -> hi/lo ----
__global__ __launch_bounds__(256) void k_l1(const float* y, const float* S1,
        const float* Ahat, unsigned short* nh, unsigned short* nl) {
    int t = blockIdx.x, g = threadIdx.x;
    float yv = y[(size_t)t * DGc + g];
#pragma unroll
    for (int n = 0; n < Nc; n++) {
        float c = Ahat[n * Nc + Ec];
        float s = silu_f(S1[n * DGc + g] + c * yv);
        unsigned short h, l;
        split2(s, h, l);
        size_t o = ((size_t)t * Nc + n) * DGc + g;
        nh[o] = h; nl[o] = l;
    }
}

// ---- mix: node[t,n] = silu(sum_m A[n,m] Z[t,m]) -> hi/lo ----
__global__ __launch_bounds__(256) void k_mix2(const float* Z, const float* Ahat,
        unsigned short* nh, unsigned short* nl) {
    int t = blockIdx.x, g = threadIdx.x;
    __shared__ float A[Nc * Nc];
    if (g < Nc * Nc) A[g] = Ahat[g];
    __syncthreads();
    float z[Nc];
#pragma unroll
    for (int m = 0; m < Nc; m++) z[m] = Z[((size_t)t * Nc + m) * DGc + g];
#pragma unroll
    for (int n = 0; n < Nc; n++) {
        float s = 0.f;
#pragma unroll
        for (int m = 0; m < Nc; m++) s += A[n * Nc + m] * z[m];
        s = silu_f(s);
        unsigned short h, l;
        split2(s, h, l);
        size_t o = ((size_t)t * Nc + n) * DGc + g;
        nh[o] = h; nl[o] = l;
    }
}

// ---- final mix + logits + softmax + top2 + routing (1 wave per token) ----
__global__ __launch_bounds__(256) void k_mix3(const float* Z, const float* Ahat,
        const float* wproj, float* out, int* cnt, int* toklist, float* wlist) {
    __shared__ float A[Nc * Nc];
    __shared__ float wp[DGc];
    int tid = threadIdx.x;
    if (tid < Nc * Nc) A[tid] = Ahat[tid];
    wp[tid] = wproj[tid];
    __syncthreads();
    int wid = tid >> 6, lane = tid & 63;
    int t = blockIdx.x * 4 + wid;
    float lg[Ec];
#pragma unroll
    for (int e = 0; e < Ec; e++) lg[e] = 0.f;
#pragma unroll
    for (int j = 0; j < 4; j++) {
        int g = j * 64 + lane;
        float z[Nc];
#pragma unroll
        for (int m = 0; m < Nc; m++) z[m] = Z[((size_t)t * Nc + m) * DGc + g];
#pragma unroll
        for (int e = 0; e < Ec; e++) {
            float s = 0.f;
#pragma unroll
            for (int m = 0; m < Nc; m++) s += A[e * Nc + m] * z[m];
            lg[e] += silu_f(s) * wp[g];
        }
    }
#pragma unroll
    for (int off = 32; off >= 1; off >>= 1) {
#pragma unroll
        for (int e = 0; e < Ec; e++) lg[e] += __shfl_xor(lg[e], off);
    }
    if (lane == 0) {
        float mx = -1e30f;
#pragma unroll
        for (int e = 0; e < Ec; e++) mx = fmaxf(mx, lg[e]);
        float pr[Ec], s = 0.f;
#pragma unroll
        for (int e = 0; e < Ec; e++) { pr[e] = __expf(lg[e] - mx); s += pr[e]; }
        float inv = 1.f / s;
        float* lrow = out + (size_t)TT * Dm + (size_t)t * Ec;
#pragma unroll
        for (int e = 0; e < Ec; e++) { pr[e] *= inv; lrow[e] = pr[e]; }
        int i0 = 0; float v0 = pr[0];
#pragma unroll
        for (int e = 1; e < Ec; e++) if (pr[e] > v0) { v0 = pr[e]; i0 = e; }
        int i1 = -1; float v1 = -1e30f;
#pragma unroll
        for (int e = 0; e < Ec; e++) if (e != i0 && pr[e] > v1) { v1 = pr[e]; i1 = e; }
        float* rowT = out + (size_t)TT * Dm + (size_t)TT * Ec;
        atomicAdd(&rowT[i0], 2.f * v0);
        atomicAdd(&rowT[i1], 2.f * v1);
        float winv = 1.f / (v0 + v1);
        int p0 = atomicAdd(&cnt[i0], 1);
        toklist[i0 * TT + p0] = t; wlist[i0 * TT + p0] = v0 * winv;
        int p1 = atomicAdd(&cnt[i1], 1);
        toklist[i1 * TT + p1] = t; wlist[i1 * TT + p1] = v1 * winv;
    }
}

// ---- padded offsets + tile map ----
__global__ void k_offs(const int* cnt, int* poffs, int* tile_e, int* tile_m0) {
    if (threadIdx.x == 0) {
        int pad = 0, nt = 0;
        for (int e = 0; e < Ec; e++) {
            poffs[e] = pad;
            int te = (cnt[e] + 127) >> 7;
            for (int i = 0; i < te; i++) { tile_e[nt] = e; tile_m0[nt] = pad + i * 128; nt++; }
            pad += te * 128;
        }
        poffs[Ec] = pad;
        for (; nt < NTILE_MAX; nt++) { tile_e[nt] = -1; tile_m0[nt] = 0; }
    }
}

// ---- gather routed tokens into padded slot-major bf16 buffer + slot maps ----
__global__ __launch_bounds__(256) void k_gather(const float* hs, const int* cnt,
        const int* poffs, const int* toklist, const float* wlist,
        unsigned short* xb, int* tokslot, float* wslot) {
    int tid = threadIdx.x;
    int s = blockIdx.x * 2 + (tid >> 7);
    int j = (tid & 127) * 8;
    int e = 0;
#pragma unroll
    for (int q = 1; q < Ec; q++) if (s >= poffs[q]) e = q;
    int pos = s - poffs[e];
    int tok = -1; float w = 0.f;
    if (pos < cnt[e]) { tok = toklist[e * TT + pos]; w = wlist[e * TT + pos]; }
    if (j == 0) { tokslot[s] = tok; wslot[s] = w; }
    ushort4 o0, o1;
    if (tok >= 0) {
        const float* xr = hs + (size_t)tok * Dm + j;
        o0.x = bf16_rne(xr[0]); o0.y = bf16_rne(xr[1]); o0.z = bf16_rne(xr[2]); o0.w = bf16_rne(xr[3]);
        o1.x = bf16_rne(xr[4]); o1.y = bf16_rne(xr[5]); o1.z = bf16_rne(xr[6]); o1.w = bf16_rne(xr[7]);
    } else {
        o0 = make_ushort4(0, 0, 0, 0); o1 = o0;
    }
    *(ushort4*)&xb[(size_t)s * Dm + j] = o0;
    *(ushort4*)&xb[(size_t)s * Dm + j + 4] = o1;
}

// ---- FFN MFMA grouped GEMM, 1D grid + XCD-chunked remap + LDS swizzle ----
template<int KDIM, int NDIM, int MODE>
__global__ __launch_bounds__(256) void k_mfma(const unsigned short* Abuf,
        const unsigned short* Wt, const int* tile_e, const int* tile_m0,
        const int* tokslot, const float* wslot, void* outp) {
    constexpr int NY = NDIM / 128;
    constexpr int CPX = (NTILE_MAX * NY) / 8;   // blocks per XCD chunk
    int bid = blockIdx.x;
    int flat = (bid & 7) * CPX + (bid >> 3);    // XCD gets contiguous x-range
    int tx = flat / NY, y = flat % NY;
    int e = tile_e[tx];
    if (e < 0) return;
    int m0 = tile_m0[tx];
    int n0 = y * 128;
    const unsigned short* Bg = Wt + (size_t)e * NDIM * KDIM;
    __shared__ __align__(16) unsigned short As[128 * 32];
    __shared__ __align__(16) unsigned short Bs[128 * 32];
    int tid = threadIdx.x;
    int lane = tid & 63;
    int wid = tid >> 6;
    int wr = wid >> 1, wc = wid & 1;
    int lo = lane & 15, hi = lane >> 4;

    f32x4 acc[4][4];
#pragma unroll
    for (int m = 0; m < 4; m++)
#pragma unroll
        for (int n = 0; n < 4; n++) acc[m][n] = (f32x4)(0.f);

    int arow = tid >> 2;
    int sW = (tid >> 3) & 3;                     // (arow>>1)&3
    int acol = ((tid & 3) ^ sW) * 8;             // pre-swizzled source col-block
    int hixor = (hi ^ ((lo >> 1) & 3)) * 8;      // swizzled read offset
    const unsigned short* Ag = Abuf + (size_t)m0 * KDIM;
    const unsigned short* Bt = Bg + (size_t)n0 * KDIM;

    for (int kb = 0; kb < KDIM; kb += 32) {
        gll16(Ag + (size_t)arow * KDIM + kb + acol,        (char*)As + tid * 16);
        gll16(Ag + (size_t)(arow + 64) * KDIM + kb + acol, (char*)As + 4096 + tid * 16);
        gll16(Bt + (size_t)arow * KDIM + kb + acol,        (char*)Bs + tid * 16);
        gll16(Bt + (size_t)(arow + 64) * KDIM + kb + acol, (char*)Bs + 4096 + tid * 16);
        __syncthreads();
        short8v a[4], b[4];
#pragma unroll
        for (int m = 0; m < 4; m++)
            a[m] = *(const short8v*)&As[(wr * 64 + m * 16 + lo) * 32 + hixor];
#pragma unroll
        for (int n = 0; n < 4; n++)
            b[n] = *(const short8v*)&Bs[(wc * 64 + n * 16 + lo) * 32 + hixor];
#pragma unroll
        for (int m = 0; m < 4; m++)
#pragma unroll
            for (int n = 0; n < 4; n++)
                acc[m][n] = __builtin_amdgcn_mfma_f32_16x16x32_bf16(a[m], b[n], acc[m][n], 0, 0, 0);
        __syncthreads();
    }

    if (MODE == 0) {
        unsigned short* O = (unsigned short*)outp;
#pragma unroll
        for (int m = 0; m < 4; m++) {
#pragma unroll
            for (int n = 0; n < 4; n++) {
                int col = n0 + wc * 64 + n * 16 + lo;
#pragma unroll
                for (int r = 0; r < 4; r++) {
                    int row = m0 + wr * 64 + m * 16 + hi * 4 + r;
                    O[(size_t)row * NDIM + col] = bf16_rne(silu_f(acc[m][n][r]));
                }
            }
        }
    } else {
        float* O = (float*)outp;
#pragma unroll
        for (int m = 0; m < 4; m++) {
            int toks[4]; float ws[4];
#pragma unroll
            for (int r = 0; r < 4; r++) {
                int row = m0 + wr * 64 + m * 16 + hi * 4 + r;
                toks[r] = tokslot[row];
                ws[r] = wslot[row];
            }
#pragma unroll
            for (int n = 0; n < 4; n++) {
                int col = n0 + wc * 64 + n * 16 + lo;
#pragma unroll
                for (int r = 0; r < 4; r++) {
                    if (toks[r] >= 0)
                        atomicAdd(&O[(size_t)toks[r] * Dm + col], ws[r] * acc[m][n][r]);
                }
            }
        }
    }
}

extern "C" void kernel_launch(void* const* d_in, const int* in_sizes, int n_in,
                              void* d_out, int out_size, void* d_ws, size_t ws_size,
                              hipStream_t stream) {
    const float* hs    = (const float*)d_in[0];
    const float* X     = (const float*)d_in[1];
    const float* Wmlp  = (const float*)d_in[2];
    const float* Wst   = (const float*)d_in[3];
    const float* convW = (const float*)d_in[4];
    const float* wproj = (const float*)d_in[5];
    const float* W1    = (const float*)d_in[6];
    const float* W2    = (const float*)d_in[7];
    const float* lamb  = (const float*)d_in[8];
    const float* theta = (const float*)d_in[9];
    const float* count = (const float*)d_in[10];
    const float* Ahat  = (const float*)d_in[11];
    float* out = (float*)d_out;
    char* ws = (char*)d_ws;

    // persistent layout
    float*          expg    = (float*)ws;                       // raw accum (silu on read)
    int*            cnt     = (int*)(ws + 8192);
    int*            poffs   = (int*)(ws + 8320);
    int*            tile_e  = (int*)(ws + 8448);
    int*            tile_m0 = (int*)(ws + 8704);
    float*          S1      = (float*)(ws + 9216);
    int*            toklist = (int*)(ws + 20480);
    float*          wlist   = (float*)(ws + 86016);
    int*            tokslot = (int*)(ws + 151552);
    float*          wslot   = (float*)(ws + 172032);
    unsigned short* xb      = (unsigned short*)(ws + 196608);   // 10.5 MB
    unsigned short* W1T     = (unsigned short*)(ws + 10682368); // 33.5 MB
    unsigned short* W2T     = (unsigned short*)(ws + 44236800); // 33.5 MB
    unsigned short* hb      = (unsigned short*)(ws + 77791232); // 21 MB

    // gate-phase temporaries aliased over the (not-yet-written) W1T/W2T region
    char* G = ws + 10682368;
    unsigned short* hs_hi = (unsigned short*)(G);
    unsigned short* hs_lo = (unsigned short*)(G + 4194304);
    unsigned short* WmT_h = (unsigned short*)(G + 8388608);
    unsigned short* WmT_l = (unsigned short*)(G + 8912896);
    unsigned short* WcT_h = (unsigned short*)(G + 9437184);
    unsigned short* WcT_l = (unsigned short*)(G + 9830400);
    unsigned short* xg_h  = (unsigned short*)(G + 10223616);
    unsigned short* xg_l  = (unsigned short*)(G + 11272192);
    float*          yb    = (float*)(G + 12320768);
    unsigned short* n_h   = (unsigned short*)(G + 14417920);
    unsigned short* n_l   = (unsigned short*)(G + 23855104);
    float*          Zb    = (float*)(G + 33292288);
    float*          Gbuf  = (float*)(G + 52166656);

    k_init<<<1, 64, 0, stream>>>(count, lamb, theta, out, cnt);
    hipMemsetAsync(expg, 0, Ec * DGc * sizeof(float), stream);
    hipMemsetAsync(Gbuf, 0, Ec * DGc * sizeof(float), stream);
    k_split<<<1024, 256, 0, stream>>>(hs, hs_hi, hs_lo);
    k_tsplit<<<dim3(DGc / 32, Dm / 32, 1), 256, 0, stream>>>(Wmlp, WmT_h, WmT_l, Dm, DGc);
    k_tsplit<<<dim3(DGc / 32, DGc / 32, 3), 256, 0, stream>>>(convW, WcT_h, WcT_l, DGc, DGc);
    k_expgA<<<Dm / 64, 256, 0, stream>>>(X, Wst, expg);
    k_gA<<<DGc / 32, 256, 0, stream>>>(expg, convW, Gbuf);
    k_s1fin<<<1, 256, 0, stream>>>(Gbuf, Ahat, S1);
    // xg = silu(hs @ Wmlp) -> hi/lo
    gemm4s<64, Dm, 1><<<dim3(TT / 64, 2), 256, 0, stream>>>(
        hs_hi, hs_lo, WmT_h, WmT_l, nullptr, xg_h, xg_l);
    // y = xg @ convW[0]
    gemm4s<64, DGc, 0><<<dim3(TT / 64, 2), 256, 0, stream>>>(
        xg_h, xg_l, WcT_h, WcT_l, yb, nullptr, nullptr);
    k_l1<<<TT, 256, 0, stream>>>(yb, S1, Ahat, n_h, n_l);
    // layer 2
    gemm4s<128, DGc, 0><<<dim3(TT * Nc / 128, 2), 256, 0, stream>>>(
        n_h, n_l, WcT_h + 65536, WcT_l + 65536, Zb, nullptr, nullptr);
    k_mix2<<<TT, 256, 0, stream>>>(Zb, Ahat, n_h, n_l);
    // layer 3
    gemm4s<128, DGc, 0><<<dim3(TT * Nc / 128, 2), 256, 0, stream>>>(
        n_h, n_l, WcT_h + 131072, WcT_l + 131072, Zb, nullptr, nullptr);
    k_mix3<<<TT / 4, 256, 0, stream>>>(Zb, Ahat, wproj, out, cnt, toklist, wlist);
    // gate temporaries dead; now build FFN weights over that region
    k_tcast<<<dim3(Hc / 32, Dm / 32, Ec), 256, 0, stream>>>(W1, W1T, Dm, Hc);
    k_tcast<<<dim3(Dm / 32, Hc / 32, Ec), 256, 0, stream>>>(W2, W2T, Hc, Dm);
    k_offs<<<1, 1, 0, stream>>>(cnt, poffs, tile_e, tile_m0);
    k_gather<<<PADMAX / 2, 256, 0, stream>>>(hs, cnt, poffs, toklist, wlist,
                                             xb, tokslot, wslot);
    hipMemsetAsync(d_out, 0, (size_t)TT * Dm * sizeof(float), stream);
    k_mfma<Dm, Hc, 0><<<NTILE_MAX * (Hc / 128), 256, 0, stream>>>(
        xb, W1T, tile_e, tile_m0, tokslot, wslot, hb);
    k_mfma<Hc, Dm, 1><<<NTILE_MAX * (Dm / 128), 256, 0, stream>>>(
        hb, W2T, tile_e, tile_m0, tokslot, wslot, out);
}